// Round 7
// baseline (2769.374 us; speedup 1.0000x reference)
//
#include <hip/hip_runtime.h>
#include <hip/hip_bf16.h>
#include <math.h>

static constexpr int BATCH = 8;
static constexpr int LL1 = 2048;
static constexpr int LL2 = 1024;
static constexpr int DMODEL = 512;
static constexpr int NHEADS = 8;
static constexpr int DKH = 64;
static constexpr int TPRED = 100;

typedef unsigned short u16;
typedef unsigned int u32;
typedef unsigned long long u64;
typedef __attribute__((ext_vector_type(8))) short short8;   // 8 bf16
typedef __attribute__((ext_vector_type(4))) float f32x4;

__device__ __forceinline__ float sigm(float x) { return 1.0f / (1.0f + expf(-x)); }

// bf16 split helpers (round-to-nearest-even)
__device__ __forceinline__ u16 f2b(float f) {
  u32 u = __builtin_bit_cast(u32, f);
  return (u16)((u + 0x7fffu + ((u >> 16) & 1u)) >> 16);
}
__device__ __forceinline__ float b2f(u16 h) {
  return __builtin_bit_cast(float, (u32)h << 16);
}

#define GLD16(gsrc, ldst) __builtin_amdgcn_global_load_lds( \
    (const __attribute__((address_space(1))) u32*)(gsrc),   \
    (__attribute__((address_space(3))) u32*)(ldst), 16, 0, 0)

// ---------------- embedding + posenc, writes fp32 + bf16-split -------------
__global__ void k_embed(const float* __restrict__ x, const float* __restrict__ ew,
                        const float* __restrict__ eb, float* __restrict__ out,
                        u16* __restrict__ oh, u16* __restrict__ ol) {
  int row = blockIdx.x;
  int l = row & (LL1 - 1);
  int tid = threadIdx.x;
  __shared__ float xr[64];
  if (tid < 64) xr[tid] = x[row * 64 + tid];
  __syncthreads();
  const float fac = -9.210340371976184f / 512.0f;
  for (int c = tid; c < DMODEL; c += 256) {
    float acc = eb[c];
#pragma unroll 8
    for (int i = 0; i < 64; i++) acc = fmaf(xr[i], ew[i * DMODEL + c], acc);
    float divv = expf((float)(2 * (c >> 1)) * fac);
    float ang = (float)l * divv;
    acc += (c & 1) ? cosf(ang) : sinf(ang);
    size_t o = (size_t)row * DMODEL + c;
    out[o] = acc;
    u16 hh = f2b(acc);
    oh[o] = hh;
    ol[o] = f2b(acc - b2f(hh));
  }
}

// ---------------- MFMA GEMM, bf16x2 split, C = A@B + bias ------------------
template <int EPI, int CONV, int OSPLIT>
__global__ __launch_bounds__(256) void k_mgemm(
    const u16* __restrict__ Ah, const u16* __restrict__ Al,
    const u16* __restrict__ Bh, const u16* __restrict__ Bl,
    const float* __restrict__ bias,
    float* __restrict__ C, u16* __restrict__ Ch, u16* __restrict__ Cl,
    int M, int N, int K, int Lc,
    const float* __restrict__ p_m, const float* __restrict__ p_v,
    const float* __restrict__ p_g, const float* __restrict__ p_b) {
  __shared__ __align__(16) u16 As_h[4096], As_l[4096], Bs_h[4096], Bs_l[4096];
  const int tid = threadIdx.x;
  const int m0 = blockIdx.y * 128, n0 = blockIdx.x * 128;
  const int wid = tid >> 6, lane = tid & 63;
  const int wm = (wid & 1) * 64, wn = (wid >> 1) * 64;
  const int lr = lane >> 4, lc = lane & 15;
  f32x4 acc[4][4];
  f32x4 zz = {0.f, 0.f, 0.f, 0.f};
#pragma unroll
  for (int i = 0; i < 4; i++)
#pragma unroll
    for (int j = 0; j < 4; j++) acc[i][j] = zz;

  for (int k0 = 0; k0 < K; k0 += 32) {
#pragma unroll
    for (int pass = 0; pass < 2; pass++) {
      int c = tid + pass * 256;
      int mi = c >> 2, kc = (c & 3) * 8;
      size_t asrc;
      if (CONV) {
        int m = m0 + mi;
        int b = m >> 11, t = m & (LL1 - 1);      // Lc == LL1 (pow2)
        int kblk = k0 >> 9;
        int srow = (b << 11) + ((t + kblk - 1 + LL1) & (LL1 - 1));
        asrc = (size_t)srow * 512 + (k0 - (kblk << 9)) + kc;
      } else {
        asrc = (size_t)(m0 + mi) * K + k0 + kc;
      }
      size_t bsrc = (size_t)(n0 + mi) * K + k0 + kc;
      u32 ldo = (u32)((wid * 64 + pass * 256) * 8);
      GLD16(Ah + asrc, As_h + ldo);
      GLD16(Al + asrc, As_l + ldo);
      GLD16(Bh + bsrc, Bs_h + ldo);
      GLD16(Bl + bsrc, Bs_l + ldo);
    }
    __syncthreads();
    short8 ah[4], alv[4], bh[4], blv[4];
#pragma unroll
    for (int i = 0; i < 4; i++) {
      int ar = (wm + i * 16 + lc) * 32 + lr * 8;
      int br = (wn + i * 16 + lc) * 32 + lr * 8;
      ah[i] = *(const short8*)&As_h[ar];
      alv[i] = *(const short8*)&As_l[ar];
      bh[i] = *(const short8*)&Bs_h[br];
      blv[i] = *(const short8*)&Bs_l[br];
    }
#pragma unroll
    for (int i = 0; i < 4; i++)
#pragma unroll
      for (int j = 0; j < 4; j++) {
        acc[i][j] = __builtin_amdgcn_mfma_f32_16x16x32_bf16(ah[i], bh[j], acc[i][j], 0, 0, 0);
        acc[i][j] = __builtin_amdgcn_mfma_f32_16x16x32_bf16(ah[i], blv[j], acc[i][j], 0, 0, 0);
        acc[i][j] = __builtin_amdgcn_mfma_f32_16x16x32_bf16(alv[i], bh[j], acc[i][j], 0, 0, 0);
      }
    __syncthreads();
  }
#pragma unroll
  for (int j = 0; j < 4; j++) {
    int col = n0 + wn + j * 16 + lc;
    float bs = bias[col];
    float bnA = 0.f, bnB = 0.f;
    if (EPI == 2) {
      bnA = rsqrtf(p_v[col] + 1e-5f) * p_g[col];
      bnB = p_b[col] - p_m[col] * bnA;
    }
#pragma unroll
    for (int i = 0; i < 4; i++) {
#pragma unroll
      for (int q = 0; q < 4; q++) {
        int row = m0 + wm + i * 16 + lr * 4 + q;
        float t = acc[i][j][q] + bs;
        if (EPI == 1) t = 0.5f * t * (1.0f + erff(t * 0.7071067811865475f));
        if (EPI == 2) { t = t * bnA + bnB; t = t > 0.f ? t : expm1f(t); }
        size_t o = (size_t)row * N + col;
        if (OSPLIT) {
          u16 hh = f2b(t);
          Ch[o] = hh;
          Cl[o] = f2b(t - b2f(hh));
        } else {
          C[o] = t;
        }
      }
    }
  }
}

// ---------------- fused weight split/transpose (all weights, 1 dispatch) ---
__global__ void k_splitall(const float* __restrict__ wq, const float* __restrict__ wk,
                           const float* __restrict__ wv, const float* __restrict__ wo,
                           const float* __restrict__ w1, const float* __restrict__ w2,
                           const float* __restrict__ cw,
                           u16* __restrict__ WATT, u16* __restrict__ W1T,
                           u16* __restrict__ W2T, u16* __restrict__ CWT) {
  int job = blockIdx.y;
  int g = blockIdx.x * 256 + threadIdx.x;
  float v;
  u16 *dh, *dl;
  if (job < 8) {
    if (g >= 262144) return;
    int l = job >> 2, mi = job & 3;
    const float* src = (mi == 0 ? wq : mi == 1 ? wk : mi == 2 ? wv : wo) + (size_t)l * 262144;
    int n = g >> 9, k = g & 511;
    v = src[(size_t)k * 512 + n];
    dh = WATT + (size_t)((l * 4 + mi) * 2) * 262144;
    dl = dh + 262144;
  } else if (job == 8 || job == 10) {           // w1: K=512, N=2048
    if (g >= 1048576) return;
    int l = (job == 10);
    int n = g >> 9, k = g & 511;
    v = w1[(size_t)l * 1048576 + (size_t)k * 2048 + n];
    dh = W1T + (size_t)(l * 2) * 1048576;
    dl = dh + 1048576;
  } else if (job == 9 || job == 11) {           // w2: K=2048, N=512
    if (g >= 1048576) return;
    int l = (job == 11);
    int n = g >> 11, k = g & 2047;
    v = w2[(size_t)l * 1048576 + (size_t)k * 512 + n];
    dh = W2T + (size_t)(l * 2) * 1048576;
    dl = dh + 1048576;
  } else {                                       // conv
    if (g >= 786432) return;
    int c = g / 1536, k = g - c * 1536;
    int kblk = k >> 9, ci = k & 511;
    v = cw[c * 1536 + ci * 3 + kblk];
    dh = CWT;
    dl = CWT + 786432;
  }
  u16 hh = f2b(v);
  dh[g] = hh;
  dl[g] = f2b(v - b2f(hh));
}

// ---------------- sampled qk -> sparsity measure M -------------------------
__global__ void k_qk_m(const float* __restrict__ Q, const float* __restrict__ Km,
                       const int* __restrict__ idx, float* __restrict__ Mout,
                       int Lc, int u) {
  int row = blockIdx.x;
  int b = row / Lc, l = row - b * Lc;
  int tid = threadIdx.x;
  int nt = blockDim.x;
  __shared__ __align__(16) float qlds[DMODEL];
  __shared__ int ilds[40];
  __shared__ float qk[320];
  for (int i = tid; i < DMODEL; i += nt) qlds[i] = Q[(size_t)row * DMODEL + i];
  for (int i = tid; i < u; i += nt) ilds[i] = idx[l * u + i];
  __syncthreads();
  int tot = NHEADS * u;
  if (tid < tot) {
    int j = tid >> 3, h = tid & 7;
    int key = ilds[j];
    const float4* kp = reinterpret_cast<const float4*>(&Km[((size_t)b * Lc + key) * DMODEL + h * DKH]);
    const float4* qp = reinterpret_cast<const float4*>(&qlds[h * DKH]);
    float s = 0.f;
#pragma unroll
    for (int d = 0; d < 16; d++) {
      float4 kv = kp[d], qv = qp[d];
      s += qv.x * kv.x + qv.y * kv.y + qv.z * kv.z + qv.w * kv.w;
    }
    qk[tid] = s;
  }
  __syncthreads();
  if (tid < NHEADS) {
    int h = tid;
    float mx = -INFINITY, sm = 0.f;
    for (int j = 0; j < u; j++) {
      float v = qk[(j << 3) + h];
      mx = fmaxf(mx, v);
      sm += v;
    }
    Mout[((size_t)b * NHEADS + h) * Lc + l] = mx - sm / (float)Lc;
  }
}

// ---------------- top-u via packed u64 keys + wave shuffles ----------------
__global__ void k_topk(const float* __restrict__ Mv, int* __restrict__ mtop,
                       int Lc, int u) {
  int bh = blockIdx.x;
  int tid = threadIdx.x;
  int lane = tid & 63, wv = tid >> 6;
  __shared__ float vals[2048];
  __shared__ u64 wred[4];
  for (int i = tid; i < Lc; i += 256) vals[i] = Mv[(size_t)bh * Lc + i];
  __syncthreads();
  for (int it = 0; it < u; it++) {
    u64 best = 0;
    for (int i = tid; i < Lc; i += 256) {
      u32 ub = __builtin_bit_cast(u32, vals[i]);
      ub = (ub & 0x80000000u) ? ~ub : (ub | 0x80000000u);
      u64 key = ((u64)ub << 32) | (u64)(0xFFFFFFFFu - (u32)i);   // lower idx wins ties
      best = best > key ? best : key;
    }
#pragma unroll
    for (int o = 32; o > 0; o >>= 1) {
      u64 other = __shfl_xor(best, o);
      best = best > other ? best : other;
    }
    if (lane == 0) wred[wv] = best;
    __syncthreads();
    u64 b01 = wred[0] > wred[1] ? wred[0] : wred[1];
    u64 b23 = wred[2] > wred[3] ? wred[2] : wred[3];
    u64 b0 = b01 > b23 ? b01 : b23;
    int bi = (int)(0xFFFFFFFFu - (u32)(b0 & 0xFFFFFFFFu));
    if (tid == 0) {
      mtop[bh * u + it] = bi;
      vals[bi] = -INFINITY;
    }
    __syncthreads();
  }
}

// ---------------- column-sum two-phase -------------------------------------
__global__ void k_colsum1(const float* __restrict__ src, float* __restrict__ part,
                          int Lc, int rp) {
  int b = blockIdx.x, ch = blockIdx.y, c = threadIdx.x;
  const float* p = src + ((size_t)b * Lc + (size_t)ch * rp) * 512 + c;
  float s = 0.f;
  for (int r = 0; r < rp; r++) s += p[(size_t)r * 512];
  part[((b << 5) + ch) * 512 + c] = s;
}
__global__ void k_colsum2(const float* __restrict__ part, float* __restrict__ of,
                          u16* __restrict__ oh, u16* __restrict__ ol,
                          int nch, float scale) {
  int b = blockIdx.x, c = threadIdx.x;
  float s = 0.f;
  for (int i = 0; i < nch; i++) s += part[(b * nch + i) * 512 + c];
  s *= scale;
  if (of) of[b * 512 + c] = s;
  if (oh) {
    u16 hh = f2b(s);
    oh[b * 512 + c] = hh;
    ol[b * 512 + c] = f2b(s - b2f(hh));
  }
}

// ---------------- fill context (bf16-split) with V-mean --------------------
__global__ void k_ctx_fillb(u16* __restrict__ ch, u16* __restrict__ cl,
                            const u16* __restrict__ vh, const u16* __restrict__ vl,
                            int Lc) {
  int g = blockIdx.x * 256 + threadIdx.x;
  int total = BATCH * Lc * 128;
  if (g >= total) return;
  int c4 = g & 127;
  int row = g >> 7;
  int b = row / Lc;
  ((ushort4*)ch)[g] = ((const ushort4*)vh)[b * 128 + c4];
  ((ushort4*)cl)[g] = ((const ushort4*)vl)[b * 128 + c4];
}

// ---------------- attention: 5 queries per block + scatter -----------------
__global__ __launch_bounds__(256) void k_attn_mq(
    const float* __restrict__ Q, const float* __restrict__ Km,
    const float* __restrict__ V, const int* __restrict__ mtop,
    u16* __restrict__ ctxh, u16* __restrict__ ctxl, int Lc, int u, int nqb) {
  int blk = blockIdx.x;
  int qb = blk % nqb;
  int bh = blk / nqb;
  int h = bh & 7, b = bh >> 3;
  int tid = threadIdx.x;
  int lane = tid & 63, wv = tid >> 6;
  __shared__ __align__(16) float qlds[5][64];
  __shared__ float s_lds[5][2048];
  __shared__ float wredA[4], wredB[4];
  __shared__ int rows_s[5];
  __shared__ float part[4][5][64];
  // load 5 query vectors (strided: 320 elements with 256 threads)
  for (int qq = tid; qq < 320; qq += 256) {
    int q = qq >> 6, d = qq & 63;
    int row = mtop[(b * 8 + h) * u + qb * 5 + q];
    if (d == 0) rows_s[q] = row;
    qlds[q][d] = Q[((size_t)b * Lc + row) * DMODEL + h * DKH + d];
  }
  __syncthreads();
  // scores: K row reused across the 5 queries
  for (int k = tid; k < Lc; k += 256) {
    const float4* kp = reinterpret_cast<const float4*>(&Km[((size_t)b * Lc + k) * DMODEL + h * DKH]);
    float s0 = 0, s1 = 0, s2 = 0, s3 = 0, s4 = 0;
#pragma unroll
    for (int d = 0; d < 16; d++) {
      float4 kv = kp[d];
      float4 q0 = ((const float4*)qlds[0])[d];
      float4 q1 = ((const float4*)qlds[1])[d];
      float4 q2 = ((const float4*)qlds[2])[d];
      float4 q3 = ((const float4*)qlds[3])[d];
      float4 q4 = ((const float4*)qlds[4])[d];
      s0 += q0.x * kv.x + q0.y * kv.y + q0.z * kv.z + q0.w * kv.w;
      s1 += q1.x * kv.x + q1.y * kv.y + q1.z * kv.z + q1.w * kv.w;
      s2 += q2.x * kv.x + q2.y * kv.y + q2.z * kv.z + q2.w * kv.w;
      s3 += q3.x * kv.x + q3.y * kv.y + q3.z * kv.z + q3.w * kv.w;
      s4 += q4.x * kv.x + q4.y * kv.y + q4.z * kv.z + q4.w * kv.w;
    }
    s_lds[0][k] = s0 * 0.125f;
    s_lds[1][k] = s1 * 0.125f;
    s_lds[2][k] = s2 * 0.125f;
    s_lds[3][k] = s3 * 0.125f;
    s_lds[4][k] = s4 * 0.125f;
  }
  __syncthreads();
  float denomv[5];
#pragma unroll
  for (int q = 0; q < 5; q++) {
    float mx = -INFINITY;
    for (int k = tid; k < Lc; k += 256) mx = fmaxf(mx, s_lds[q][k]);
#pragma unroll
    for (int o = 32; o > 0; o >>= 1) mx = fmaxf(mx, __shfl_xor(mx, o));
    if (lane == 0) wredA[wv] = mx;
    __syncthreads();
    mx = fmaxf(fmaxf(wredA[0], wredA[1]), fmaxf(wredA[2], wredA[3]));
    float ls = 0.f;
    for (int k = tid; k < Lc; k += 256) {
      float w = expf(s_lds[q][k] - mx);
      s_lds[q][k] = w;
      ls += w;
    }
#pragma unroll
    for (int o = 32; o > 0; o >>= 1) ls += __shfl_xor(ls, o);
    if (lane == 0) wredB[wv] = ls;
    __syncthreads();
    denomv[q] = (wredB[0] + wredB[1]) + (wredB[2] + wredB[3]);
  }
  // PV: V row reused across queries; 4 k-chunks x 64 dims
  float acc0 = 0, acc1 = 0, acc2 = 0, acc3 = 0, acc4 = 0;
  int chunk = Lc >> 2;
  for (int k = wv * chunk; k < (wv + 1) * chunk; k++) {
    float vvv = V[((size_t)b * Lc + k) * DMODEL + h * DKH + lane];
    acc0 = fmaf(s_lds[0][k], vvv, acc0);
    acc1 = fmaf(s_lds[1][k], vvv, acc1);
    acc2 = fmaf(s_lds[2][k], vvv, acc2);
    acc3 = fmaf(s_lds[3][k], vvv, acc3);
    acc4 = fmaf(s_lds[4][k], vvv, acc4);
  }
  part[wv][0][lane] = acc0;
  part[wv][1][lane] = acc1;
  part[wv][2][lane] = acc2;
  part[wv][3][lane] = acc3;
  part[wv][4][lane] = acc4;
  __syncthreads();
  for (int q = wv; q < 5; q += 4) {
    float tot = ((part[0][q][lane] + part[1][q][lane]) +
                 (part[2][q][lane] + part[3][q][lane])) / denomv[q];
    size_t o = ((size_t)b * Lc + rows_s[q]) * DMODEL + h * DKH + lane;
    u16 hh = f2b(tot);
    ctxh[o] = hh;
    ctxl[o] = f2b(tot - b2f(hh));
  }
}

// ---------------- y = LayerNorm(x+a)*g+b ; optional fp32 / split out -------
__global__ void k_add_ln(const float* __restrict__ x, const float* __restrict__ a,
                         const float* __restrict__ g, const float* __restrict__ be,
                         float* __restrict__ y, u16* __restrict__ yh,
                         u16* __restrict__ yl) {
  int row = blockIdx.x;
  int tid = threadIdx.x;
  __shared__ float red[256];
  float2 xv = reinterpret_cast<const float2*>(x)[(size_t)row * 256 + tid];
  float2 av = reinterpret_cast<const float2*>(a)[(size_t)row * 256 + tid];
  float vx = xv.x + av.x, vy = xv.y + av.y;
  red[tid] = vx + vy;
  __syncthreads();
  for (int s = 128; s > 0; s >>= 1) {
    if (tid < s) red[tid] += red[tid + s];
    __syncthreads();
  }
  float mean = red[0] * (1.0f / 512.0f);
  __syncthreads();
  float dx = vx - mean, dy = vy - mean;
  red[tid] = dx * dx + dy * dy;
  __syncthreads();
  for (int s = 128; s > 0; s >>= 1) {
    if (tid < s) red[tid] += red[tid + s];
    __syncthreads();
  }
  float rstd = rsqrtf(red[0] * (1.0f / 512.0f) + 1e-5f);
  int c = tid * 2;
  float ox = dx * rstd * g[c] + be[c];
  float oy = dy * rstd * g[c + 1] + be[c + 1];
  if (y) {
    float2 o = {ox, oy};
    reinterpret_cast<float2*>(y)[(size_t)row * 256 + tid] = o;
  }
  if (yh) {
    size_t base = (size_t)row * 512 + c;
    u16 h0 = f2b(ox), h1 = f2b(oy);
    yh[base] = h0; yh[base + 1] = h1;
    yl[base] = f2b(ox - b2f(h0));
    yl[base + 1] = f2b(oy - b2f(h1));
  }
}

// ---------------- maxpool k=3 s=2, fp32 + split out ------------------------
__global__ void k_pool(const float* __restrict__ cv, float* __restrict__ out,
                       u16* __restrict__ oh, u16* __restrict__ ol) {
  int g = blockIdx.x * 256 + threadIdx.x;
  int total = BATCH * LL2 * DMODEL;
  if (g >= total) return;
  int c = g & 511;
  int rest = g >> 9;
  int i = rest & (LL2 - 1);
  int b = rest >> 10;
  int t0 = 2 * i - 1;
  float m = -INFINITY;
#pragma unroll
  for (int k = 0; k < 3; k++) {
    int t = t0 + k;
    if (t >= 0 && t < LL1) m = fmaxf(m, cv[((size_t)b * LL1 + t) * DMODEL + c]);
  }
  out[g] = m;
  u16 hh = f2b(m);
  oh[g] = hh;
  ol[g] = f2b(m - b2f(hh));
}

// ---------------- gx = enc @ wih^T + bih (+ zero lstm flags) ---------------
__global__ void k_gx(const float* __restrict__ enc, const float* __restrict__ wih,
                     const float* __restrict__ bih, float* __restrict__ gx,
                     unsigned* __restrict__ flags) {
  int g = blockIdx.x * 256 + threadIdx.x;
  if (g < 64) flags[g] = 0u;
  if (g >= BATCH * 2048) return;
  int b = g >> 11, j = g & 2047;
  const float4* wp = reinterpret_cast<const float4*>(&wih[(size_t)j * 512]);
  const float4* ep = reinterpret_cast<const float4*>(&enc[b * 512]);
  float s = bih[j];
  for (int d = 0; d < 128; d++) {
    float4 w = wp[d], e = ep[d];
    s += w.x * e.x + w.y * e.y + w.z * e.z + w.w * e.w;
  }
  gx[g] = s;
}

// ---------------- persistent LSTM v4 ---------------------------------------
// 65 blocks x 256 thr. Blocks 0-63: block bl owns h-cols [bl*8,bl*8+8) x 8
// batches; weights in 16 NAMED float4 registers (SSA -> VGPRs, no scratch).
// Block 64: pure output consumer (polls flags, reads h, computes out dots) so
// compute blocks have identical work (no skew). Parity double-buffered hglob;
// relaxed agent atomics write-through; batched coherent sc0/sc1 read.
#define MACB(W, RO)                                                     \
  {                                                                     \
    _Pragma("unroll")                                                   \
    for (int b = 0; b < 8; b++) {                                       \
      float4 hv = *(const float4*)&h_s[b * 512 + koff + (RO)];          \
      p[b] = fmaf(W.x, hv.x, p[b]);                                     \
      p[b] = fmaf(W.y, hv.y, p[b]);                                     \
      p[b] = fmaf(W.z, hv.z, p[b]);                                     \
      p[b] = fmaf(W.w, hv.w, p[b]);                                     \
    }                                                                   \
  }

__global__ __launch_bounds__(256, 1) void k_lstm4(
    const float* __restrict__ gx, const float* __restrict__ whh,
    const float* __restrict__ bhh, const float* __restrict__ ow,
    const float* __restrict__ ob, float* __restrict__ out,
    float* __restrict__ hglob, unsigned* __restrict__ flags) {
  const int bl = blockIdx.x, tid = threadIdx.x;
  const bool outblk = (bl >= 64);
  const int part = tid >> 5, idx = tid & 31;       // part: 64-chunk of k
  const int gtype = idx >> 3, ml = idx & 7;
  const int koff = part * 64;
  __shared__ float h_s[4096];                       // [b][512]
  __shared__ float red[8][8][32];                   // [b][part][idx]
  __shared__ float gvs[8][32];                      // [b][idx]
  __shared__ float ow_s[512];
  float4 w0, w1, w2, w3, w4, w5, w6, w7, w8, w9, w10, w11, w12, w13, w14, w15;
  float gxrow = 0.f, cst = 0.f;
  int j = 0;
  if (!outblk) {
    j = gtype * 512 + bl * 8 + ml;                  // owned gate row
    const float4* wr = (const float4*)&whh[(size_t)j * 512 + koff];
    w0 = wr[0];  w1 = wr[1];  w2 = wr[2];  w3 = wr[3];
    w4 = wr[4];  w5 = wr[5];  w6 = wr[6];  w7 = wr[7];
    w8 = wr[8];  w9 = wr[9];  w10 = wr[10]; w11 = wr[11];
    w12 = wr[12]; w13 = wr[13]; w14 = wr[14]; w15 = wr[15];
    gxrow = gx[part * 2048 + j] + bhh[j];           // (b=part, row j)
  }
  for (int i = tid; i < 4096; i += 256) h_s[i] = 0.f;
  for (int i = tid; i < 512; i += 256) ow_s[i] = ow[i];
  const float obv = ob[0];
  __syncthreads();
  for (int t = 0; t < TPRED; t++) {
    if (!outblk) {
      // partial matvec: 64-chunk dot of row j against h for all 8 batches
      float p[8];
#pragma unroll
      for (int b = 0; b < 8; b++) p[b] = 0.f;
      MACB(w0, 0)  MACB(w1, 4)  MACB(w2, 8)  MACB(w3, 12)
      MACB(w4, 16) MACB(w5, 20) MACB(w6, 24) MACB(w7, 28)
      MACB(w8, 32) MACB(w9, 36) MACB(w10, 40) MACB(w11, 44)
      MACB(w12, 48) MACB(w13, 52) MACB(w14, 56) MACB(w15, 60)
#pragma unroll
      for (int b = 0; b < 8; b++) red[b][part][idx] = p[b];
      __syncthreads();
      float gv = gxrow;                             // (b=part, row idx)
#pragma unroll
      for (int pp = 0; pp < 8; pp++) gv += red[part][pp][idx];
      gvs[part][idx] = gv;                          // [b][idx]
      __syncthreads();
      float* hgb = hglob + ((t + 1) & 1) * 4096;    // parity buffer
      if (tid < 64) {                               // (b, ml) owners
        int b = tid >> 3, m = tid & 7;
        float gi = gvs[b][m], gf = gvs[b][8 + m];
        float gg = gvs[b][16 + m], go = gvs[b][24 + m];
        float c = sigm(gf) * cst + sigm(gi) * tanhf(gg);
        cst = c;
        float hn = sigm(go) * tanhf(c);
        __hip_atomic_store(&hgb[b * 512 + bl * 8 + m], hn, __ATOMIC_RELAXED,
                           __HIP_MEMORY_SCOPE_AGENT);
      }
      __syncthreads();   // vmcnt(0) drained: h stores at coherent point
      if (tid == 0)
        __hip_atomic_store(&flags[bl], (unsigned)(t + 1), __ATOMIC_RELAXED,
                           __HIP_MEMORY_SCOPE_AGENT);
    }
    if (tid < 64) {
      while (__hip_atomic_load(&flags[tid], __ATOMIC_RELAXED,
                               __HIP_MEMORY_SCOPE_AGENT) < (unsigned)(t + 1)) {}
    }
    __syncthreads();
    asm volatile("" ::: "memory");
    {
      const float4* hp = (const float4*)(hglob + ((t + 1) & 1) * 4096);
      float4 r0, r1, r2, r3;
      asm volatile("global_load_dwordx4 %0, %1, off sc0 sc1"
                   : "=v"(r0) : "v"(hp + tid) : "memory");
      asm volatile("global_load_dwordx4 %0, %1, off sc0 sc1"
                   : "=v"(r1) : "v"(hp + tid + 256) : "memory");
      asm volatile("global_load_dwordx4 %0, %1, off sc0 sc1"
                   : "=v"(r2) : "v"(hp + tid + 512) : "memory");
      asm volatile("global_load_dwordx4 %0, %1, off sc0 sc1"
                   : "=v"(r3) : "v"(hp + tid + 768) : "memory");
      asm volatile("s_waitcnt vmcnt(0)" ::: "memory");
      ((float4*)h_s)[tid] = r0;
      ((float4*)h_s)[tid + 256] = r1;
      ((float4*)h_s)[tid + 512] = r2;
      ((float4*)h_s)[tid + 768] = r3;
    }
    __syncthreads();
    if (outblk) {                                   // output dots, all batches
      int b = tid >> 5, l5 = tid & 31;
      float s = 0.f;
#pragma unroll
      for (int e = 0; e < 16; e++) s += h_s[b * 512 + l5 + e * 32] * ow_s[l5 + e * 32];
#pragma unroll
      for (int o = 16; o > 0; o >>= 1) s += __shfl_xor(s, o);
      if (l5 == 0) out[b * TPRED + t] = s + obv;
    }
  }
}

// ---------------------------------------------------------------------------
extern "C" void kernel_launch(void* const* d_in, const int* in_sizes, int n_in,
                              void* d_out, int out_size, void* d_ws, size_t ws_size,
                              hipStream_t stream) {
  const float* x = (const float*)d_in[0];
  const int* idx1 = (const int*)d_in[1];
  const int* idx2 = (const int*)d_in[2];
  const float* emb_w = (const float*)d_in[3];
  const float* emb_b = (const float*)d_in[4];
  const float* wq = (const float*)d_in[5];
  const float* bq = (const float*)d_in[6];
  const float* wk = (const float*)d_in[7];
  const float* bk = (const float*)d_in[8];
  const float* wv = (const float*)d_in[9];
  const float* bv = (const float*)d_in[10];
  const float* wo = (const float*)d_in[11];
  const float* bo = (const float*)d_in[12];
  const float* w1 = (const float*)d_in[13];
  const float* b1 = (const float*)d_in[14];
  const float* w2 = (const float*)d_in[15];
  const float* b2 = (const float*)d_in[16];
  const float* ln1g = (const float*)d_in[17];
  const float* ln1b = (const float*)d_in[18];
  const float* ln2g = (const float*)d_in[19];
  const float* ln2b = (const float*)d_in[20];
  const float* conv_w = (const float*)d_in[21];
  const float* conv_b = (const float*)d_in[22];
  const float* bn_g = (const float*)d_in[23];
  const float* bn_b = (const float*)d_in[24];
  const float* bn_m = (const float*)d_in[25];
  const float* bn_v = (const float*)d_in[26];
  const float* lstm_wih = (const float*)d_in[27];
  const float* lstm_whh = (const float*)d_in[28];
  const float* lstm_bih = (const float*)d_in[29];
  const float* lstm_bhh = (const float*)d_in[30];
  const float* out_w = (const float*)d_in[31];
  const float* out_b = (const float*)d_in[32];
  float* outp = (float*)d_out;

  char* ws = (char*)d_ws;
  const size_t MB = 1 << 20;
  float* S0 = (float*)(ws);
  float* S1 = (float*)(ws + 32 * MB);
  float* S2 = (float*)(ws + 64 * MB);
  float* S3 = (float*)(ws + 96 * MB);
  u16* P0 = (u16*)(ws + 128 * MB);
  u16* P1 = (u16*)(ws + 144 * MB);
  u16* P2 = (u16*)(ws + 160 * MB);
  u16* P3 = (u16*)(ws + 176 * MB);
  u16* WATT = (u16*)(ws + 192 * MB);
  u16* W1T = (u16*)(ws + 200 * MB);
  u16* W2T = (u16*)(ws + 208 * MB);
  u16* CWT = (u16*)(ws + 216 * MB);
  char* SMB = ws + 220 * MB;
  float* Mbuf = (float*)(SMB);                       // 512 KB
  float* csp = (float*)(SMB + 512 * 1024);           // 512 KB
  u16* vmh = (u16*)(SMB + 1040 * 1024);
  u16* vml = (u16*)(SMB + 1048 * 1024);
  int* mtop = (int*)(SMB + 1056 * 1024);
  float* gxb = (float*)(SMB + 1088 * 1024);          // 64 KB
  float* encb = (float*)(SMB + 1152 * 1024);
  float* hglob = (float*)(SMB + 1168 * 1024);        // 32 KB (2x4096 floats)
  unsigned* flags = (unsigned*)(SMB + 1216 * 1024);

  auto wat = [&](int l, int m, int hl) {
    return WATT + ((size_t)((l * 4 + m) * 2 + hl)) * 262144;
  };

  // fused weight split (single dispatch)
  {
    dim3 g(4096, 13);
    k_splitall<<<g, 256, 0, stream>>>(wq, wk, wv, wo, w1, w2, conv_w,
                                      WATT, W1T, W2T, CWT);
  }

  auto mg = [&](const u16* Ah, const u16* Al, const u16* Bh, const u16* Bl,
                const float* bias, float* C, int M, int N, int K) {
    dim3 g(N / 128, M / 128);
    k_mgemm<0, 0, 0><<<g, 256, 0, stream>>>(Ah, Al, Bh, Bl, bias, C, nullptr, nullptr,
                                            M, N, K, 0, nullptr, nullptr, nullptr, nullptr);
  };

  // ---------------- embed ----------------
  k_embed<<<BATCH * LL1, 256, 0, stream>>>(x, emb_w, emb_b, S0, P0, P1);

  // ---------------- encoder layer 1 (L=2048, u=40) ----------------
  {
    const int Lc = LL1, u = 40, M = BATCH * LL1;
    mg(P0, P1, wat(0, 0, 0), wat(0, 0, 1), bq, S1, M, 512, 512);
    mg(P0, P1, wat(0, 1, 0), wat(0, 1, 1), bk, S2, M, 512, 512);
    mg(P0, P1, wat(0, 2, 0), wat(0, 2, 1), bv, S3, M, 512, 512);
    k_qk_m<<<M, 320, 0, stream>>>(S1, S2, idx1, Mbuf, Lc, u);
    k_topk<<<64, 256, 0, stream>>>(Mbuf, mtop, Lc, u);
    k_colsum1<<<dim3(BATCH, 32), 512, 0, stream>>>(S3, csp, Lc, Lc / 32);
    k_colsum2<<<BATCH, 512, 0, stream>>>(csp, nullptr, vmh, vml, 32, 1.f / Lc);
    k_ctx_fillb<<<(BATCH * Lc * 128) / 256, 256, 0, stream>>>(P2, P3, vmh, vml, Lc);
    k_attn_mq<<<64 * 8, 256, 0, stream>>>(S1, S2, S3, mtop, P2, P3, Lc, u, 8);
    mg(P2, P3, wat(0, 3, 0), wat(0, 3, 1), bo, S1, M, 512, 512);
    k_add_ln<<<M, 256, 0, stream>>>(S0, S1, ln1g, ln1b, S2, P0, P1);
    u16* hidh = (u16*)S0;
    u16* hidl = (u16*)S1;
    for (int c = 0; c < 2; c++) {
      dim3 g1(16, 64);
      k_mgemm<1, 0, 1><<<g1, 256, 0, stream>>>(
          P0 + (size_t)c * 8192 * 512, P1 + (size_t)c * 8192 * 512,
          W1T, W1T + 1048576, b1, nullptr, hidh, hidl, 8192, 2048, 512, 0,
          nullptr, nullptr, nullptr, nullptr);
      dim3 g2(4, 64);
      k_mgemm<0, 0, 0><<<g2, 256, 0, stream>>>(
          hidh, hidl, W2T, W2T + 1048576, b2, S3 + (size_t)c * 8192 * 512,
          nullptr, nullptr, 8192, 512, 2048, 0, nullptr, nullptr, nullptr, nullptr);
    }
    k_add_ln<<<M, 256, 0, stream>>>(S2, S3, ln2g, ln2b, nullptr, P0, P1);
  }

  // ---------------- conv distill ----------------
  {
    dim3 g(4, 128);
    k_mgemm<2, 1, 0><<<g, 256, 0, stream>>>(P0, P1, CWT, CWT + 786432, conv_b,
                                            S1, nullptr, nullptr, 16384, 512, 1536,
                                            LL1, bn_m, bn_v, bn_g, bn_b);
    k_pool<<<(BATCH * LL2 * 512) / 256, 256, 0, stream>>>(S1, S2, P0, P1);
  }

  // ---------------- encoder layer 2 (L=1024, u=35) ----------------
  {
    const int Lc = LL2, u = 35, M = BATCH * LL2;
    float* Qb = S1;
    float* Kb = S1 + 4194304;
    float* Vb = S3;
    float* AOb = S3 + 4194304;
    mg(P0, P1, wat(1, 0, 0), wat(1, 0, 1), bq + 512, Qb, M, 512, 512);
    mg(P0, P1, wat(1, 1, 0), wat(1, 1, 1), bk + 512, Kb, M, 512, 512);
    mg(P0, P1, wat(1, 2, 0), wat(1, 2, 1), bv + 512, Vb, M, 512, 512);
    k_qk_m<<<M, 320, 0, stream>>>(Qb, Kb, idx2, Mbuf, Lc, u);
    k_topk<<<64, 256, 0, stream>>>(Mbuf, mtop, Lc, u);
    k_colsum1<<<dim3(BATCH, 32), 512, 0, stream>>>(Vb, csp, Lc, Lc / 32);
    k_colsum2<<<BATCH, 512, 0, stream>>>(csp, nullptr, vmh, vml, 32, 1.f / Lc);
    k_ctx_fillb<<<(BATCH * Lc * 128) / 256, 256, 0, stream>>>(P2, P3, vmh, vml, Lc);
    k_attn_mq<<<64 * 7, 256, 0, stream>>>(Qb, Kb, Vb, mtop, P2, P3, Lc, u, 7);
    mg(P2, P3, wat(1, 3, 0), wat(1, 3, 1), bo + 512, AOb, M, 512, 512);
    k_add_ln<<<M, 256, 0, stream>>>(S2, AOb, ln1g + 512, ln1b + 512, S0, P0, P1);
    u16* hidh = (u16*)S1;
    u16* hidl = (u16*)S3;
    {
      dim3 g1(16, 64);
      k_mgemm<1, 0, 1><<<g1, 256, 0, stream>>>(
          P0, P1, W1T + (size_t)2 * 1048576, W1T + (size_t)3 * 1048576, b1 + 2048,
          nullptr, hidh, hidl, 8192, 2048, 512, 0, nullptr, nullptr, nullptr, nullptr);
      dim3 g2(4, 64);
      k_mgemm<0, 0, 0><<<g2, 256, 0, stream>>>(
          hidh, hidl, W2T + (size_t)2 * 1048576, W2T + (size_t)3 * 1048576, b2 + 512,
          S2, nullptr, nullptr, 8192, 512, 2048, 0, nullptr, nullptr, nullptr, nullptr);
    }
    k_add_ln<<<M, 256, 0, stream>>>(S0, S2, ln2g + 512, ln2b + 512, S3, nullptr, nullptr);
  }

  // ---------------- mean -> LSTM -> output ----------------
  k_colsum1<<<dim3(BATCH, 32), 512, 0, stream>>>(S3, csp, LL2, LL2 / 32);
  k_colsum2<<<BATCH, 512, 0, stream>>>(csp, encb, nullptr, nullptr, 32, 1.f / LL2);
  k_gx<<<(BATCH * 2048) / 256, 256, 0, stream>>>(encb, lstm_wih, lstm_bih, gxb, flags);
  k_lstm4<<<65, 256, 0, stream>>>(gxb, lstm_whh, lstm_bhh, out_w, out_b, outp,
                                  hglob, flags);
}

// Round 8
// 2494.698 us; speedup vs baseline: 1.1101x; 1.1101x over previous
//
#include <hip/hip_runtime.h>
#include <hip/hip_bf16.h>
#include <math.h>

static constexpr int BATCH = 8;
static constexpr int LL1 = 2048;
static constexpr int LL2 = 1024;
static constexpr int DMODEL = 512;
static constexpr int NHEADS = 8;
static constexpr int DKH = 64;
static constexpr int TPRED = 100;

typedef unsigned short u16;
typedef unsigned int u32;
typedef unsigned long long u64;
typedef __attribute__((ext_vector_type(8))) short short8;   // 8 bf16
typedef __attribute__((ext_vector_type(4))) float f32x4;

__device__ __forceinline__ float sigm(float x) { return 1.0f / (1.0f + expf(-x)); }

// bf16 split helpers (round-to-nearest-even)
__device__ __forceinline__ u16 f2b(float f) {
  u32 u = __builtin_bit_cast(u32, f);
  return (u16)((u + 0x7fffu + ((u >> 16) & 1u)) >> 16);
}
__device__ __forceinline__ float b2f(u16 h) {
  return __builtin_bit_cast(float, (u32)h << 16);
}

#define GLD16(gsrc, ldst) __builtin_amdgcn_global_load_lds( \
    (const __attribute__((address_space(1))) u32*)(gsrc),   \
    (__attribute__((address_space(3))) u32*)(ldst), 16, 0, 0)

// ---------------- embedding + posenc, writes fp32 + bf16-split -------------
__global__ void k_embed(const float* __restrict__ x, const float* __restrict__ ew,
                        const float* __restrict__ eb, float* __restrict__ out,
                        u16* __restrict__ oh, u16* __restrict__ ol) {
  int row = blockIdx.x;
  int l = row & (LL1 - 1);
  int tid = threadIdx.x;
  __shared__ float xr[64];
  if (tid < 64) xr[tid] = x[row * 64 + tid];
  __syncthreads();
  const float fac = -9.210340371976184f / 512.0f;
  for (int c = tid; c < DMODEL; c += 256) {
    float acc = eb[c];
#pragma unroll 8
    for (int i = 0; i < 64; i++) acc = fmaf(xr[i], ew[i * DMODEL + c], acc);
    float divv = expf((float)(2 * (c >> 1)) * fac);
    float ang = (float)l * divv;
    acc += (c & 1) ? cosf(ang) : sinf(ang);
    size_t o = (size_t)row * DMODEL + c;
    out[o] = acc;
    u16 hh = f2b(acc);
    oh[o] = hh;
    ol[o] = f2b(acc - b2f(hh));
  }
}

// ---------------- MFMA GEMM, bf16x2 split, C = A@B + bias ------------------
template <int EPI, int CONV, int OSPLIT>
__global__ __launch_bounds__(256) void k_mgemm(
    const u16* __restrict__ Ah, const u16* __restrict__ Al,
    const u16* __restrict__ Bh, const u16* __restrict__ Bl,
    const float* __restrict__ bias,
    float* __restrict__ C, u16* __restrict__ Ch, u16* __restrict__ Cl,
    int M, int N, int K, int Lc,
    const float* __restrict__ p_m, const float* __restrict__ p_v,
    const float* __restrict__ p_g, const float* __restrict__ p_b) {
  __shared__ __align__(16) u16 As_h[4096], As_l[4096], Bs_h[4096], Bs_l[4096];
  const int tid = threadIdx.x;
  const int m0 = blockIdx.y * 128, n0 = blockIdx.x * 128;
  const int wid = tid >> 6, lane = tid & 63;
  const int wm = (wid & 1) * 64, wn = (wid >> 1) * 64;
  const int lr = lane >> 4, lc = lane & 15;
  f32x4 acc[4][4];
  f32x4 zz = {0.f, 0.f, 0.f, 0.f};
#pragma unroll
  for (int i = 0; i < 4; i++)
#pragma unroll
    for (int j = 0; j < 4; j++) acc[i][j] = zz;

  for (int k0 = 0; k0 < K; k0 += 32) {
#pragma unroll
    for (int pass = 0; pass < 2; pass++) {
      int c = tid + pass * 256;
      int mi = c >> 2, kc = (c & 3) * 8;
      size_t asrc;
      if (CONV) {
        int m = m0 + mi;
        int b = m >> 11, t = m & (LL1 - 1);      // Lc == LL1 (pow2)
        int kblk = k0 >> 9;
        int srow = (b << 11) + ((t + kblk - 1 + LL1) & (LL1 - 1));
        asrc = (size_t)srow * 512 + (k0 - (kblk << 9)) + kc;
      } else {
        asrc = (size_t)(m0 + mi) * K + k0 + kc;
      }
      size_t bsrc = (size_t)(n0 + mi) * K + k0 + kc;
      u32 ldo = (u32)((wid * 64 + pass * 256) * 8);
      GLD16(Ah + asrc, As_h + ldo);
      GLD16(Al + asrc, As_l + ldo);
      GLD16(Bh + bsrc, Bs_h + ldo);
      GLD16(Bl + bsrc, Bs_l + ldo);
    }
    __syncthreads();
    short8 ah[4], alv[4], bh[4], blv[4];
#pragma unroll
    for (int i = 0; i < 4; i++) {
      int ar = (wm + i * 16 + lc) * 32 + lr * 8;
      int br = (wn + i * 16 + lc) * 32 + lr * 8;
      ah[i] = *(const short8*)&As_h[ar];
      alv[i] = *(const short8*)&As_l[ar];
      bh[i] = *(const short8*)&Bs_h[br];
      blv[i] = *(const short8*)&Bs_l[br];
    }
#pragma unroll
    for (int i = 0; i < 4; i++)
#pragma unroll
      for (int j = 0; j < 4; j++) {
        acc[i][j] = __builtin_amdgcn_mfma_f32_16x16x32_bf16(ah[i], bh[j], acc[i][j], 0, 0, 0);
        acc[i][j] = __builtin_amdgcn_mfma_f32_16x16x32_bf16(ah[i], blv[j], acc[i][j], 0, 0, 0);
        acc[i][j] = __builtin_amdgcn_mfma_f32_16x16x32_bf16(alv[i], bh[j], acc[i][j], 0, 0, 0);
      }
    __syncthreads();
  }
#pragma unroll
  for (int j = 0; j < 4; j++) {
    int col = n0 + wn + j * 16 + lc;
    float bs = bias[col];
    float bnA = 0.f, bnB = 0.f;
    if (EPI == 2) {
      bnA = rsqrtf(p_v[col] + 1e-5f) * p_g[col];
      bnB = p_b[col] - p_m[col] * bnA;
    }
#pragma unroll
    for (int i = 0; i < 4; i++) {
#pragma unroll
      for (int q = 0; q < 4; q++) {
        int row = m0 + wm + i * 16 + lr * 4 + q;
        float t = acc[i][j][q] + bs;
        if (EPI == 1) t = 0.5f * t * (1.0f + erff(t * 0.7071067811865475f));
        if (EPI == 2) { t = t * bnA + bnB; t = t > 0.f ? t : expm1f(t); }
        size_t o = (size_t)row * N + col;
        if (OSPLIT) {
          u16 hh = f2b(t);
          Ch[o] = hh;
          Cl[o] = f2b(t - b2f(hh));
        } else {
          C[o] = t;
        }
      }
    }
  }
}

// ---------------- fused weight split/transpose (all weights, 1 dispatch) ---
__global__ void k_splitall(const float* __restrict__ wq, const float* __restrict__ wk,
                           const float* __restrict__ wv, const float* __restrict__ wo,
                           const float* __restrict__ w1, const float* __restrict__ w2,
                           const float* __restrict__ cw,
                           u16* __restrict__ WATT, u16* __restrict__ W1T,
                           u16* __restrict__ W2T, u16* __restrict__ CWT) {
  int job = blockIdx.y;
  int g = blockIdx.x * 256 + threadIdx.x;
  float v;
  u16 *dh, *dl;
  if (job < 8) {
    if (g >= 262144) return;
    int l = job >> 2, mi = job & 3;
    const float* src = (mi == 0 ? wq : mi == 1 ? wk : mi == 2 ? wv : wo) + (size_t)l * 262144;
    int n = g >> 9, k = g & 511;
    v = src[(size_t)k * 512 + n];
    dh = WATT + (size_t)((l * 4 + mi) * 2) * 262144;
    dl = dh + 262144;
  } else if (job == 8 || job == 10) {           // w1: K=512, N=2048
    if (g >= 1048576) return;
    int l = (job == 10);
    int n = g >> 9, k = g & 511;
    v = w1[(size_t)l * 1048576 + (size_t)k * 2048 + n];
    dh = W1T + (size_t)(l * 2) * 1048576;
    dl = dh + 1048576;
  } else if (job == 9 || job == 11) {           // w2: K=2048, N=512
    if (g >= 1048576) return;
    int l = (job == 11);
    int n = g >> 11, k = g & 2047;
    v = w2[(size_t)l * 1048576 + (size_t)k * 512 + n];
    dh = W2T + (size_t)(l * 2) * 1048576;
    dl = dh + 1048576;
  } else {                                       // conv
    if (g >= 786432) return;
    int c = g / 1536, k = g - c * 1536;
    int kblk = k >> 9, ci = k & 511;
    v = cw[c * 1536 + ci * 3 + kblk];
    dh = CWT;
    dl = CWT + 786432;
  }
  u16 hh = f2b(v);
  dh[g] = hh;
  dl[g] = f2b(v - b2f(hh));
}

// ---------------- sampled qk -> sparsity measure M -------------------------
__global__ void k_qk_m(const float* __restrict__ Q, const float* __restrict__ Km,
                       const int* __restrict__ idx, float* __restrict__ Mout,
                       int Lc, int u) {
  int row = blockIdx.x;
  int b = row / Lc, l = row - b * Lc;
  int tid = threadIdx.x;
  int nt = blockDim.x;
  __shared__ __align__(16) float qlds[DMODEL];
  __shared__ int ilds[40];
  __shared__ float qk[320];
  for (int i = tid; i < DMODEL; i += nt) qlds[i] = Q[(size_t)row * DMODEL + i];
  for (int i = tid; i < u; i += nt) ilds[i] = idx[l * u + i];
  __syncthreads();
  int tot = NHEADS * u;
  if (tid < tot) {
    int j = tid >> 3, h = tid & 7;
    int key = ilds[j];
    const float4* kp = reinterpret_cast<const float4*>(&Km[((size_t)b * Lc + key) * DMODEL + h * DKH]);
    const float4* qp = reinterpret_cast<const float4*>(&qlds[h * DKH]);
    float s = 0.f;
#pragma unroll
    for (int d = 0; d < 16; d++) {
      float4 kv = kp[d], qv = qp[d];
      s += qv.x * kv.x + qv.y * kv.y + qv.z * kv.z + qv.w * kv.w;
    }
    qk[tid] = s;
  }
  __syncthreads();
  if (tid < NHEADS) {
    int h = tid;
    float mx = -INFINITY, sm = 0.f;
    for (int j = 0; j < u; j++) {
      float v = qk[(j << 3) + h];
      mx = fmaxf(mx, v);
      sm += v;
    }
    Mout[((size_t)b * NHEADS + h) * Lc + l] = mx - sm / (float)Lc;
  }
}

// ---------------- top-u via packed u64 keys + wave shuffles ----------------
__global__ void k_topk(const float* __restrict__ Mv, int* __restrict__ mtop,
                       int Lc, int u) {
  int bh = blockIdx.x;
  int tid = threadIdx.x;
  int lane = tid & 63, wv = tid >> 6;
  __shared__ float vals[2048];
  __shared__ u64 wred[4];
  for (int i = tid; i < Lc; i += 256) vals[i] = Mv[(size_t)bh * Lc + i];
  __syncthreads();
  for (int it = 0; it < u; it++) {
    u64 best = 0;
    for (int i = tid; i < Lc; i += 256) {
      u32 ub = __builtin_bit_cast(u32, vals[i]);
      ub = (ub & 0x80000000u) ? ~ub : (ub | 0x80000000u);
      u64 key = ((u64)ub << 32) | (u64)(0xFFFFFFFFu - (u32)i);   // lower idx wins ties
      best = best > key ? best : key;
    }
#pragma unroll
    for (int o = 32; o > 0; o >>= 1) {
      u64 other = __shfl_xor(best, o);
      best = best > other ? best : other;
    }
    if (lane == 0) wred[wv] = best;
    __syncthreads();
    u64 b01 = wred[0] > wred[1] ? wred[0] : wred[1];
    u64 b23 = wred[2] > wred[3] ? wred[2] : wred[3];
    u64 b0 = b01 > b23 ? b01 : b23;
    int bi = (int)(0xFFFFFFFFu - (u32)(b0 & 0xFFFFFFFFu));
    if (tid == 0) {
      mtop[bh * u + it] = bi;
      vals[bi] = -INFINITY;
    }
    __syncthreads();
  }
}

// ---------------- column-sum two-phase -------------------------------------
__global__ void k_colsum1(const float* __restrict__ src, float* __restrict__ part,
                          int Lc, int rp) {
  int b = blockIdx.x, ch = blockIdx.y, c = threadIdx.x;
  const float* p = src + ((size_t)b * Lc + (size_t)ch * rp) * 512 + c;
  float s = 0.f;
  for (int r = 0; r < rp; r++) s += p[(size_t)r * 512];
  part[((b << 5) + ch) * 512 + c] = s;
}
__global__ void k_colsum2(const float* __restrict__ part, float* __restrict__ of,
                          u16* __restrict__ oh, u16* __restrict__ ol,
                          int nch, float scale) {
  int b = blockIdx.x, c = threadIdx.x;
  float s = 0.f;
  for (int i = 0; i < nch; i++) s += part[(b * nch + i) * 512 + c];
  s *= scale;
  if (of) of[b * 512 + c] = s;
  if (oh) {
    u16 hh = f2b(s);
    oh[b * 512 + c] = hh;
    ol[b * 512 + c] = f2b(s - b2f(hh));
  }
}

// ---------------- fill context (bf16-split) with V-mean --------------------
__global__ void k_ctx_fillb(u16* __restrict__ ch, u16* __restrict__ cl,
                            const u16* __restrict__ vh, const u16* __restrict__ vl,
                            int Lc) {
  int g = blockIdx.x * 256 + threadIdx.x;
  int total = BATCH * Lc * 128;
  if (g >= total) return;
  int c4 = g & 127;
  int row = g >> 7;
  int b = row / Lc;
  ((ushort4*)ch)[g] = ((const ushort4*)vh)[b * 128 + c4];
  ((ushort4*)cl)[g] = ((const ushort4*)vl)[b * 128 + c4];
}

// ---------------- attention: 5 queries per block + scatter -----------------
__global__ __launch_bounds__(256) void k_attn_mq(
    const float* __restrict__ Q, const float* __restrict__ Km,
    const float* __restrict__ V, const int* __restrict__ mtop,
    u16* __restrict__ ctxh, u16* __restrict__ ctxl, int Lc, int u, int nqb) {
  int blk = blockIdx.x;
  int qb = blk % nqb;
  int bh = blk / nqb;
  int h = bh & 7, b = bh >> 3;
  int tid = threadIdx.x;
  int lane = tid & 63, wv = tid >> 6;
  __shared__ __align__(16) float qlds[5][64];
  __shared__ float s_lds[5][2048];
  __shared__ float wredA[4], wredB[4];
  __shared__ int rows_s[5];
  __shared__ float part[4][5][64];
  // load 5 query vectors (strided: 320 elements with 256 threads)
  for (int qq = tid; qq < 320; qq += 256) {
    int q = qq >> 6, d = qq & 63;
    int row = mtop[(b * 8 + h) * u + qb * 5 + q];
    if (d == 0) rows_s[q] = row;
    qlds[q][d] = Q[((size_t)b * Lc + row) * DMODEL + h * DKH + d];
  }
  __syncthreads();
  // scores: K row reused across the 5 queries
  for (int k = tid; k < Lc; k += 256) {
    const float4* kp = reinterpret_cast<const float4*>(&Km[((size_t)b * Lc + k) * DMODEL + h * DKH]);
    float s0 = 0, s1 = 0, s2 = 0, s3 = 0, s4 = 0;
#pragma unroll
    for (int d = 0; d < 16; d++) {
      float4 kv = kp[d];
      float4 q0 = ((const float4*)qlds[0])[d];
      float4 q1 = ((const float4*)qlds[1])[d];
      float4 q2 = ((const float4*)qlds[2])[d];
      float4 q3 = ((const float4*)qlds[3])[d];
      float4 q4 = ((const float4*)qlds[4])[d];
      s0 += q0.x * kv.x + q0.y * kv.y + q0.z * kv.z + q0.w * kv.w;
      s1 += q1.x * kv.x + q1.y * kv.y + q1.z * kv.z + q1.w * kv.w;
      s2 += q2.x * kv.x + q2.y * kv.y + q2.z * kv.z + q2.w * kv.w;
      s3 += q3.x * kv.x + q3.y * kv.y + q3.z * kv.z + q3.w * kv.w;
      s4 += q4.x * kv.x + q4.y * kv.y + q4.z * kv.z + q4.w * kv.w;
    }
    s_lds[0][k] = s0 * 0.125f;
    s_lds[1][k] = s1 * 0.125f;
    s_lds[2][k] = s2 * 0.125f;
    s_lds[3][k] = s3 * 0.125f;
    s_lds[4][k] = s4 * 0.125f;
  }
  __syncthreads();
  float denomv[5];
#pragma unroll
  for (int q = 0; q < 5; q++) {
    float mx = -INFINITY;
    for (int k = tid; k < Lc; k += 256) mx = fmaxf(mx, s_lds[q][k]);
#pragma unroll
    for (int o = 32; o > 0; o >>= 1) mx = fmaxf(mx, __shfl_xor(mx, o));
    if (lane == 0) wredA[wv] = mx;
    __syncthreads();
    mx = fmaxf(fmaxf(wredA[0], wredA[1]), fmaxf(wredA[2], wredA[3]));
    float ls = 0.f;
    for (int k = tid; k < Lc; k += 256) {
      float w = expf(s_lds[q][k] - mx);
      s_lds[q][k] = w;
      ls += w;
    }
#pragma unroll
    for (int o = 32; o > 0; o >>= 1) ls += __shfl_xor(ls, o);
    if (lane == 0) wredB[wv] = ls;
    __syncthreads();
    denomv[q] = (wredB[0] + wredB[1]) + (wredB[2] + wredB[3]);
  }
  // PV: V row reused across queries; 4 k-chunks x 64 dims
  float acc0 = 0, acc1 = 0, acc2 = 0, acc3 = 0, acc4 = 0;
  int chunk = Lc >> 2;
  for (int k = wv * chunk; k < (wv + 1) * chunk; k++) {
    float vvv = V[((size_t)b * Lc + k) * DMODEL + h * DKH + lane];
    acc0 = fmaf(s_lds[0][k], vvv, acc0);
    acc1 = fmaf(s_lds[1][k], vvv, acc1);
    acc2 = fmaf(s_lds[2][k], vvv, acc2);
    acc3 = fmaf(s_lds[3][k], vvv, acc3);
    acc4 = fmaf(s_lds[4][k], vvv, acc4);
  }
  part[wv][0][lane] = acc0;
  part[wv][1][lane] = acc1;
  part[wv][2][lane] = acc2;
  part[wv][3][lane] = acc3;
  part[wv][4][lane] = acc4;
  __syncthreads();
  for (int q = wv; q < 5; q += 4) {
    float tot = ((part[0][q][lane] + part[1][q][lane]) +
                 (part[2][q][lane] + part[3][q][lane])) / denomv[q];
    size_t o = ((size_t)b * Lc + rows_s[q]) * DMODEL + h * DKH + lane;
    u16 hh = f2b(tot);
    ctxh[o] = hh;
    ctxl[o] = f2b(tot - b2f(hh));
  }
}

// ---------------- y = LayerNorm(x+a)*g+b ; optional fp32 / split out -------
__global__ void k_add_ln(const float* __restrict__ x, const float* __restrict__ a,
                         const float* __restrict__ g, const float* __restrict__ be,
                         float* __restrict__ y, u16* __restrict__ yh,
                         u16* __restrict__ yl) {
  int row = blockIdx.x;
  int tid = threadIdx.x;
  __shared__ float red[256];
  float2 xv = reinterpret_cast<const float2*>(x)[(size_t)row * 256 + tid];
  float2 av = reinterpret_cast<const float2*>(a)[(size_t)row * 256 + tid];
  float vx = xv.x + av.x, vy = xv.y + av.y;
  red[tid] = vx + vy;
  __syncthreads();
  for (int s = 128; s > 0; s >>= 1) {
    if (tid < s) red[tid] += red[tid + s];
    __syncthreads();
  }
  float mean = red[0] * (1.0f / 512.0f);
  __syncthreads();
  float dx = vx - mean, dy = vy - mean;
  red[tid] = dx * dx + dy * dy;
  __syncthreads();
  for (int s = 128; s > 0; s >>= 1) {
    if (tid < s) red[tid] += red[tid + s];
    __syncthreads();
  }
  float rstd = rsqrtf(red[0] * (1.0f / 512.0f) + 1e-5f);
  int c = tid * 2;
  float ox = dx * rstd * g[c] + be[c];
  float oy = dy * rstd * g[c + 1] + be[c + 1];
  if (y) {
    float2 o = {ox, oy};
    reinterpret_cast<float2*>(y)[(size_t)row * 256 + tid] = o;
  }
  if (yh) {
    size_t base = (size_t)row * 512 + c;
    u16 h0 = f2b(ox), h1 = f2b(oy);
    yh[base] = h0; yh[base + 1] = h1;
    yl[base] = f2b(ox - b2f(h0));
    yl[base + 1] = f2b(oy - b2f(h1));
  }
}

// ---------------- maxpool k=3 s=2, fp32 + split out ------------------------
__global__ void k_pool(const float* __restrict__ cv, float* __restrict__ out,
                       u16* __restrict__ oh, u16* __restrict__ ol) {
  int g = blockIdx.x * 256 + threadIdx.x;
  int total = BATCH * LL2 * DMODEL;
  if (g >= total) return;
  int c = g & 511;
  int rest = g >> 9;
  int i = rest & (LL2 - 1);
  int b = rest >> 10;
  int t0 = 2 * i - 1;
  float m = -INFINITY;
#pragma unroll
  for (int k = 0; k < 3; k++) {
    int t = t0 + k;
    if (t >= 0 && t < LL1) m = fmaxf(m, cv[((size_t)b * LL1 + t) * DMODEL + c]);
  }
  out[g] = m;
  u16 hh = f2b(m);
  oh[g] = hh;
  ol[g] = f2b(m - b2f(hh));
}

// ---------------- gx = enc @ wih^T + bih (+ zero lstm tag buffer) ----------
__global__ void k_gx(const float* __restrict__ enc, const float* __restrict__ wih,
                     const float* __restrict__ bih, float* __restrict__ gx,
                     u64* __restrict__ hgl) {
  int g = blockIdx.x * 256 + threadIdx.x;
  if (g < 8192) hgl[g] = 0ull;                      // zero tags (both parities)
  if (g >= BATCH * 2048) return;
  int b = g >> 11, j = g & 2047;
  const float4* wp = reinterpret_cast<const float4*>(&wih[(size_t)j * 512]);
  const float4* ep = reinterpret_cast<const float4*>(&enc[b * 512]);
  float s = bih[j];
  for (int d = 0; d < 128; d++) {
    float4 w = wp[d], e = ep[d];
    s += w.x * e.x + w.y * e.y + w.z * e.z + w.w * e.w;
  }
  gx[g] = s;
}

// ---------------- persistent LSTM v5: tagged-u64 single-RT exchange --------
// 64 blocks x 256 thr (R6 matvec/output structure). Block bl owns h-cols
// [bl*8,bl*8+8) x 8 batches. Exchange: each h element is ONE u64 agent-scope
// relaxed atomic = (tag=t+1)<<32 | float bits. Producers store right after
// computing h (atomic word carries its own readiness); consumers poll their
// 16 slots directly. No flags, no fences, one coherence round trip per step.
// Parity double-buffer; max skew 1 step (poll for t+1 gates advancement), so
// tag t+3 overwrite cannot land before all finished polling t+1.
__global__ __launch_bounds__(256, 1) void k_lstm5(
    const float* __restrict__ gx, const float* __restrict__ whh,
    const float* __restrict__ bhh, const float* __restrict__ ow,
    const float* __restrict__ ob, float* __restrict__ out,
    u64* __restrict__ hglob) {
  const int bl = blockIdx.x, tid = threadIdx.x;
  const int part = tid >> 5, idx = tid & 31;       // part: 64-chunk of k
  const int gtype = idx >> 3, ml = idx & 7;
  const int j = gtype * 512 + bl * 8 + ml;          // owned gate row
  __shared__ float h_s[4096];                       // [b][512]
  __shared__ float red[8][8][32];                   // [b][part][idx]
  __shared__ float gvs[8][32];                      // [b][idx]
  __shared__ float ow_s[512];
  __shared__ float ored[4];
  float w[64];
  {
    const float* wr = &whh[(size_t)j * 512 + part * 64];
#pragma unroll
    for (int r = 0; r < 64; r += 4) {
      float4 v = *(const float4*)&wr[r];
      w[r] = v.x; w[r + 1] = v.y; w[r + 2] = v.z; w[r + 3] = v.w;
    }
  }
  const float gxrow = gx[part * 2048 + j] + bhh[j];  // (b=part, row j)
  float cst = 0.f;                                    // live on tid<64
  for (int i = tid; i < 4096; i += 256) h_s[i] = 0.f;
  for (int i = tid; i < 512; i += 256) ow_s[i] = ow[i];
  const float obv = ob[0];
  __syncthreads();
  for (int t = 0; t < TPRED; t++) {
    // partial matvec: 64-chunk dot of row j against h for all 8 batches
    float p[8];
#pragma unroll
    for (int b = 0; b < 8; b++) p[b] = 0.f;
#pragma unroll
    for (int r = 0; r < 64; r += 4) {
      float w0 = w[r], w1 = w[r + 1], w2 = w[r + 2], w3 = w[r + 3];
#pragma unroll
      for (int b = 0; b < 8; b++) {
        float4 hv = *(const float4*)&h_s[b * 512 + part * 64 + r];
        p[b] = fmaf(w3, hv.w, fmaf(w2, hv.z, fmaf(w1, hv.y, fmaf(w0, hv.x, p[b]))));
      }
    }
#pragma unroll
    for (int b = 0; b < 8; b++) red[b][part][idx] = p[b];
    __syncthreads();
    float gv = gxrow;                                 // (b=part, row idx)
#pragma unroll
    for (int pp = 0; pp < 8; pp++) gv += red[part][pp][idx];
    gvs[part][idx] = gv;                              // [b][idx]
    __syncthreads();
    u64* hgb = hglob + ((t + 1) & 1) * 4096;          // parity buffer
    const u32 want = (u32)(t + 1);
    if (tid < 64) {                                   // (b, ml) owners
      int b = tid >> 3, m = tid & 7;
      float gi = gvs[b][m], gf = gvs[b][8 + m];
      float gg = gvs[b][16 + m], go = gvs[b][24 + m];
      float c = sigm(gf) * cst + sigm(gi) * tanhf(gg);
      cst = c;
      float hn = sigm(go) * tanhf(c);
      u64 word = ((u64)want << 32) | (u64)__builtin_bit_cast(u32, hn);
      __hip_atomic_store(&hgb[b * 512 + bl * 8 + m], word, __ATOMIC_RELAXED,
                         __HIP_MEMORY_SCOPE_AGENT);
    }
    // poll-read: each thread owns 16 slots (tagged data = single RT)
    {
      u64 v[16];
#pragma unroll
      for (int q = 0; q < 16; q++)
        v[q] = __hip_atomic_load(&hgb[q * 256 + tid], __ATOMIC_RELAXED,
                                 __HIP_MEMORY_SCOPE_AGENT);
      bool ok;
      do {
        ok = true;
#pragma unroll
        for (int q = 0; q < 16; q++) {
          if ((u32)(v[q] >> 32) != want) {
            ok = false;
            v[q] = __hip_atomic_load(&hgb[q * 256 + tid], __ATOMIC_RELAXED,
                                     __HIP_MEMORY_SCOPE_AGENT);
          }
        }
      } while (!ok);
#pragma unroll
      for (int q = 0; q < 16; q++)
        h_s[q * 256 + tid] = __builtin_bit_cast(float, (u32)(v[q] & 0xFFFFFFFFull));
    }
    __syncthreads();
    if (bl < 8) {                                     // output dot for batch bl
      float s = h_s[bl * 512 + tid] * ow_s[tid] +
                h_s[bl * 512 + 256 + tid] * ow_s[256 + tid];
#pragma unroll
      for (int o = 32; o > 0; o >>= 1) s += __shfl_xor(s, o);
      if ((tid & 63) == 0) ored[tid >> 6] = s;
      __syncthreads();
      if (tid == 0)
        out[bl * TPRED + t] = (ored[0] + ored[1]) + (ored[2] + ored[3]) + obv;
    }
  }
}

// ---------------------------------------------------------------------------
extern "C" void kernel_launch(void* const* d_in, const int* in_sizes, int n_in,
                              void* d_out, int out_size, void* d_ws, size_t ws_size,
                              hipStream_t stream) {
  const float* x = (const float*)d_in[0];
  const int* idx1 = (const int*)d_in[1];
  const int* idx2 = (const int*)d_in[2];
  const float* emb_w = (const float*)d_in[3];
  const float* emb_b = (const float*)d_in[4];
  const float* wq = (const float*)d_in[5];
  const float* bq = (const float*)d_in[6];
  const float* wk = (const float*)d_in[7];
  const float* bk = (const float*)d_in[8];
  const float* wv = (const float*)d_in[9];
  const float* bv = (const float*)d_in[10];
  const float* wo = (const float*)d_in[11];
  const float* bo = (const float*)d_in[12];
  const float* w1 = (const float*)d_in[13];
  const float* b1 = (const float*)d_in[14];
  const float* w2 = (const float*)d_in[15];
  const float* b2 = (const float*)d_in[16];
  const float* ln1g = (const float*)d_in[17];
  const float* ln1b = (const float*)d_in[18];
  const float* ln2g = (const float*)d_in[19];
  const float* ln2b = (const float*)d_in[20];
  const float* conv_w = (const float*)d_in[21];
  const float* conv_b = (const float*)d_in[22];
  const float* bn_g = (const float*)d_in[23];
  const float* bn_b = (const float*)d_in[24];
  const float* bn_m = (const float*)d_in[25];
  const float* bn_v = (const float*)d_in[26];
  const float* lstm_wih = (const float*)d_in[27];
  const float* lstm_whh = (const float*)d_in[28];
  const float* lstm_bih = (const float*)d_in[29];
  const float* lstm_bhh = (const float*)d_in[30];
  const float* out_w = (const float*)d_in[31];
  const float* out_b = (const float*)d_in[32];
  float* outp = (float*)d_out;

  char* ws = (char*)d_ws;
  const size_t MB = 1 << 20;
  float* S0 = (float*)(ws);
  float* S1 = (float*)(ws + 32 * MB);
  float* S2 = (float*)(ws + 64 * MB);
  float* S3 = (float*)(ws + 96 * MB);
  u16* P0 = (u16*)(ws + 128 * MB);
  u16* P1 = (u16*)(ws + 144 * MB);
  u16* P2 = (u16*)(ws + 160 * MB);
  u16* P3 = (u16*)(ws + 176 * MB);
  u16* WATT = (u16*)(ws + 192 * MB);
  u16* W1T = (u16*)(ws + 200 * MB);
  u16* W2T = (u16*)(ws + 208 * MB);
  u16* CWT = (u16*)(ws + 216 * MB);
  char* SMB = ws + 220 * MB;
  float* Mbuf = (float*)(SMB);                       // 512 KB
  float* csp = (float*)(SMB + 512 * 1024);           // 512 KB
  u16* vmh = (u16*)(SMB + 1040 * 1024);
  u16* vml = (u16*)(SMB + 1048 * 1024);
  int* mtop = (int*)(SMB + 1056 * 1024);
  float* gxb = (float*)(SMB + 1088 * 1024);          // 64 KB
  float* encb = (float*)(SMB + 1152 * 1024);
  u64* hglob = (u64*)(SMB + 1168 * 1024);            // 64 KB (2x4096 u64)

  auto wat = [&](int l, int m, int hl) {
    return WATT + ((size_t)((l * 4 + m) * 2 + hl)) * 262144;
  };

  // fused weight split (single dispatch)
  {
    dim3 g(4096, 13);
    k_splitall<<<g, 256, 0, stream>>>(wq, wk, wv, wo, w1, w2, conv_w,
                                      WATT, W1T, W2T, CWT);
  }

  auto mg = [&](const u16* Ah, const u16* Al, const u16* Bh, const u16* Bl,
                const float* bias, float* C, int M, int N, int K) {
    dim3 g(N / 128, M / 128);
    k_mgemm<0, 0, 0><<<g, 256, 0, stream>>>(Ah, Al, Bh, Bl, bias, C, nullptr, nullptr,
                                            M, N, K, 0, nullptr, nullptr, nullptr, nullptr);
  };

  // ---------------- embed ----------------
  k_embed<<<BATCH * LL1, 256, 0, stream>>>(x, emb_w, emb_b, S0, P0, P1);

  // ---------------- encoder layer 1 (L=2048, u=40) ----------------
  {
    const int Lc = LL1, u = 40, M = BATCH * LL1;
    mg(P0, P1, wat(0, 0, 0), wat(0, 0, 1), bq, S1, M, 512, 512);
    mg(P0, P1, wat(0, 1, 0), wat(0, 1, 1), bk, S2, M, 512, 512);
    mg(P0, P1, wat(0, 2, 0), wat(0, 2, 1), bv, S3, M, 512, 512);
    k_qk_m<<<M, 320, 0, stream>>>(S1, S2, idx1, Mbuf, Lc, u);
    k_topk<<<64, 256, 0, stream>>>(Mbuf, mtop, Lc, u);
    k_colsum1<<<dim3(BATCH, 32), 512, 0, stream>>>(S3, csp, Lc, Lc / 32);
    k_colsum2<<<BATCH, 512, 0, stream>>>(csp, nullptr, vmh, vml, 32, 1.f / Lc);
    k_ctx_fillb<<<(BATCH * Lc * 128) / 256, 256, 0, stream>>>(P2, P3, vmh, vml, Lc);
    k_attn_mq<<<64 * 8, 256, 0, stream>>>(S1, S2, S3, mtop, P2, P3, Lc, u, 8);
    mg(P2, P3, wat(0, 3, 0), wat(0, 3, 1), bo, S1, M, 512, 512);
    k_add_ln<<<M, 256, 0, stream>>>(S0, S1, ln1g, ln1b, S2, P0, P1);
    u16* hidh = (u16*)S0;
    u16* hidl = (u16*)S1;
    for (int c = 0; c < 2; c++) {
      dim3 g1(16, 64);
      k_mgemm<1, 0, 1><<<g1, 256, 0, stream>>>(
          P0 + (size_t)c * 8192 * 512, P1 + (size_t)c * 8192 * 512,
          W1T, W1T + 1048576, b1, nullptr, hidh, hidl, 8192, 2048, 512, 0,
          nullptr, nullptr, nullptr, nullptr);
      dim3 g2(4, 64);
      k_mgemm<0, 0, 0><<<g2, 256, 0, stream>>>(
          hidh, hidl, W2T, W2T + 1048576, b2, S3 + (size_t)c * 8192 * 512,
          nullptr, nullptr, 8192, 512, 2048, 0, nullptr, nullptr, nullptr, nullptr);
    }
    k_add_ln<<<M, 256, 0, stream>>>(S2, S3, ln2g, ln2b, nullptr, P0, P1);
  }

  // ---------------- conv distill ----------------
  {
    dim3 g(4, 128);
    k_mgemm<2, 1, 0><<<g, 256, 0, stream>>>(P0, P1, CWT, CWT + 786432, conv_b,
                                            S1, nullptr, nullptr, 16384, 512, 1536,
                                            LL1, bn_m, bn_v, bn_g, bn_b);
    k_pool<<<(BATCH * LL2 * 512) / 256, 256, 0, stream>>>(S1, S2, P0, P1);
  }

  // ---------------- encoder layer 2 (L=1024, u=35) ----------------
  {
    const int Lc = LL2, u = 35, M = BATCH * LL2;
    float* Qb = S1;
    float* Kb = S1 + 4194304;
    float* Vb = S3;
    float* AOb = S3 + 4194304;
    mg(P0, P1, wat(1, 0, 0), wat(1, 0, 1), bq + 512, Qb, M, 512, 512);
    mg(P0, P1, wat(1, 1, 0), wat(1, 1, 1), bk + 512, Kb, M, 512, 512);
    mg(P0, P1, wat(1, 2, 0), wat(1, 2, 1), bv + 512, Vb, M, 512, 512);
    k_qk_m<<<M, 320, 0, stream>>>(Qb, Kb, idx2, Mbuf, Lc, u);
    k_topk<<<64, 256, 0, stream>>>(Mbuf, mtop, Lc, u);
    k_colsum1<<<dim3(BATCH, 32), 512, 0, stream>>>(Vb, csp, Lc, Lc / 32);
    k_colsum2<<<BATCH, 512, 0, stream>>>(csp, nullptr, vmh, vml, 32, 1.f / Lc);
    k_ctx_fillb<<<(BATCH * Lc * 128) / 256, 256, 0, stream>>>(P2, P3, vmh, vml, Lc);
    k_attn_mq<<<64 * 7, 256, 0, stream>>>(Qb, Kb, Vb, mtop, P2, P3, Lc, u, 7);
    mg(P2, P3, wat(1, 3, 0), wat(1, 3, 1), bo + 512, AOb, M, 512, 512);
    k_add_ln<<<M, 256, 0, stream>>>(S2, AOb, ln1g + 512, ln1b + 512, S0, P0, P1);
    u16* hidh = (u16*)S1;
    u16* hidl = (u16*)S3;
    {
      dim3 g1(16, 64);
      k_mgemm<1, 0, 1><<<g1, 256, 0, stream>>>(
          P0, P1, W1T + (size_t)2 * 1048576, W1T + (size_t)3 * 1048576, b1 + 2048,
          nullptr, hidh, hidl, 8192, 2048, 512, 0, nullptr, nullptr, nullptr, nullptr);
      dim3 g2(4, 64);
      k_mgemm<0, 0, 0><<<g2, 256, 0, stream>>>(
          hidh, hidl, W2T + (size_t)2 * 1048576, W2T + (size_t)3 * 1048576, b2 + 512,
          S2, nullptr, nullptr, 8192, 512, 2048, 0, nullptr, nullptr, nullptr, nullptr);
    }
    k_add_ln<<<M, 256, 0, stream>>>(S0, S2, ln2g + 512, ln2b + 512, S3, nullptr, nullptr);
  }

  // ---------------- mean -> LSTM -> output ----------------
  k_colsum1<<<dim3(BATCH, 32), 512, 0, stream>>>(S3, csp, LL2, LL2 / 32);
  k_colsum2<<<BATCH, 512, 0, stream>>>(csp, encb, nullptr, nullptr, 32, 1.f / LL2);
  k_gx<<<(BATCH * 2048) / 256, 256, 0, stream>>>(encb, lstm_wih, lstm_bih, gxb, hglob);
  k_lstm5<<<64, 256, 0, stream>>>(gxb, lstm_whh, lstm_bhh, out_w, out_b, outp, hglob);
}

// Round 9
// 2434.624 us; speedup vs baseline: 1.1375x; 1.0247x over previous
//
#include <hip/hip_runtime.h>
#include <hip/hip_bf16.h>
#include <math.h>

static constexpr int BATCH = 8;
static constexpr int LL1 = 2048;
static constexpr int LL2 = 1024;
static constexpr int DMODEL = 512;
static constexpr int NHEADS = 8;
static constexpr int DKH = 64;
static constexpr int TPRED = 100;

typedef unsigned short u16;
typedef unsigned int u32;
typedef unsigned long long u64;
typedef __attribute__((ext_vector_type(8))) short short8;   // 8 bf16
typedef __attribute__((ext_vector_type(4))) float f32x4;

__device__ __forceinline__ float sigm(float x) { return 1.0f / (1.0f + expf(-x)); }

// bf16 split helpers (round-to-nearest-even)
__device__ __forceinline__ u16 f2b(float f) {
  u32 u = __builtin_bit_cast(u32, f);
  return (u16)((u + 0x7fffu + ((u >> 16) & 1u)) >> 16);
}
__device__ __forceinline__ float b2f(u16 h) {
  return __builtin_bit_cast(float, (u32)h << 16);
}

#define GLD16(gsrc, ldst) __builtin_amdgcn_global_load_lds( \
    (const __attribute__((address_space(1))) u32*)(gsrc),   \
    (__attribute__((address_space(3))) u32*)(ldst), 16, 0, 0)

// ---------------- embedding + posenc, 8 rows/block (ew traffic /8) ---------
__global__ void k_embed(const float* __restrict__ x, const float* __restrict__ ew,
                        const float* __restrict__ eb, float* __restrict__ out,
                        u16* __restrict__ oh, u16* __restrict__ ol) {
  int r0 = blockIdx.x * 8;          // 2048 blocks
  int tid = threadIdx.x;            // 256
  __shared__ float xr[8][64];
  for (int i = tid; i < 512; i += 256)
    xr[i >> 6][i & 63] = x[(size_t)r0 * 64 + i];
  __syncthreads();
  const float fac = -9.210340371976184f / 512.0f;
  int l0 = r0 & (LL1 - 1);
  for (int c = tid; c < DMODEL; c += 256) {
    float acc[8];
#pragma unroll
    for (int r = 0; r < 8; r++) acc[r] = eb[c];
    for (int i = 0; i < 64; i++) {
      float w = ew[i * DMODEL + c];
#pragma unroll
      for (int r = 0; r < 8; r++) acc[r] = fmaf(xr[r][i], w, acc[r]);
    }
    float divv = expf((float)(2 * (c >> 1)) * fac);
#pragma unroll
    for (int r = 0; r < 8; r++) {
      float ang = (float)(l0 + r) * divv;
      float v = acc[r] + ((c & 1) ? cosf(ang) : sinf(ang));
      size_t o = (size_t)(r0 + r) * DMODEL + c;
      out[o] = v;
      u16 hh = f2b(v);
      oh[o] = hh;
      ol[o] = f2b(v - b2f(hh));
    }
  }
}

// ---------------- MFMA GEMM, bf16x2 split, C = A@B + bias ------------------
// MULTI: N=1536 fused QKV; output routed per 512-col block to C/C1/C2,
// biases bias/bias1/bias2, each output row-stride 512.
template <int EPI, int CONV, int OSPLIT, int MULTI>
__global__ __launch_bounds__(256) void k_mgemm(
    const u16* __restrict__ Ah, const u16* __restrict__ Al,
    const u16* __restrict__ Bh, const u16* __restrict__ Bl,
    const float* __restrict__ bias, const float* __restrict__ bias1,
    const float* __restrict__ bias2,
    float* __restrict__ C, float* __restrict__ C1, float* __restrict__ C2,
    u16* __restrict__ Ch, u16* __restrict__ Cl,
    int M, int N, int K, int Lc,
    const float* __restrict__ p_m, const float* __restrict__ p_v,
    const float* __restrict__ p_g, const float* __restrict__ p_b) {
  __shared__ __align__(16) u16 As_h[4096], As_l[4096], Bs_h[4096], Bs_l[4096];
  const int tid = threadIdx.x;
  const int m0 = blockIdx.y * 128, n0 = blockIdx.x * 128;
  const int wid = tid >> 6, lane = tid & 63;
  const int wm = (wid & 1) * 64, wn = (wid >> 1) * 64;
  const int lr = lane >> 4, lc = lane & 15;
  f32x4 acc[4][4];
  f32x4 zz = {0.f, 0.f, 0.f, 0.f};
#pragma unroll
  for (int i = 0; i < 4; i++)
#pragma unroll
    for (int j = 0; j < 4; j++) acc[i][j] = zz;

  for (int k0 = 0; k0 < K; k0 += 32) {
#pragma unroll
    for (int pass = 0; pass < 2; pass++) {
      int c = tid + pass * 256;
      int mi = c >> 2, kc = (c & 3) * 8;
      size_t asrc;
      if (CONV) {
        int m = m0 + mi;
        int b = m >> 11, t = m & (LL1 - 1);      // Lc == LL1 (pow2)
        int kblk = k0 >> 9;
        int srow = (b << 11) + ((t + kblk - 1 + LL1) & (LL1 - 1));
        asrc = (size_t)srow * 512 + (k0 - (kblk << 9)) + kc;
      } else {
        asrc = (size_t)(m0 + mi) * K + k0 + kc;
      }
      size_t bsrc = (size_t)(n0 + mi) * K + k0 + kc;
      u32 ldo = (u32)((wid * 64 + pass * 256) * 8);
      GLD16(Ah + asrc, As_h + ldo);
      GLD16(Al + asrc, As_l + ldo);
      GLD16(Bh + bsrc, Bs_h + ldo);
      GLD16(Bl + bsrc, Bs_l + ldo);
    }
    __syncthreads();
    short8 ah[4], alv[4], bh[4], blv[4];
#pragma unroll
    for (int i = 0; i < 4; i++) {
      int ar = (wm + i * 16 + lc) * 32 + lr * 8;
      int br = (wn + i * 16 + lc) * 32 + lr * 8;
      ah[i] = *(const short8*)&As_h[ar];
      alv[i] = *(const short8*)&As_l[ar];
      bh[i] = *(const short8*)&Bs_h[br];
      blv[i] = *(const short8*)&Bs_l[br];
    }
#pragma unroll
    for (int i = 0; i < 4; i++)
#pragma unroll
      for (int j = 0; j < 4; j++) {
        acc[i][j] = __builtin_amdgcn_mfma_f32_16x16x32_bf16(ah[i], bh[j], acc[i][j], 0, 0, 0);
        acc[i][j] = __builtin_amdgcn_mfma_f32_16x16x32_bf16(ah[i], blv[j], acc[i][j], 0, 0, 0);
        acc[i][j] = __builtin_amdgcn_mfma_f32_16x16x32_bf16(alv[i], bh[j], acc[i][j], 0, 0, 0);
      }
    __syncthreads();
  }
#pragma unroll
  for (int j = 0; j < 4; j++) {
    int col = n0 + wn + j * 16 + lc;
    const float* bp = bias;
    float* Cp = C;
    int cw = col, Nw = N;
    if (MULTI) {
      int sel = col >> 9;
      bp = sel == 0 ? bias : (sel == 1 ? bias1 : bias2);
      Cp = sel == 0 ? C : (sel == 1 ? C1 : C2);
      cw = col & 511;
      Nw = 512;
    }
    float bs = bp[cw];
    float bnA = 0.f, bnB = 0.f;
    if (EPI == 2) {
      bnA = rsqrtf(p_v[cw] + 1e-5f) * p_g[cw];
      bnB = p_b[cw] - p_m[cw] * bnA;
    }
#pragma unroll
    for (int i = 0; i < 4; i++) {
#pragma unroll
      for (int q = 0; q < 4; q++) {
        int row = m0 + wm + i * 16 + lr * 4 + q;
        float t = acc[i][j][q] + bs;
        if (EPI == 1) t = 0.5f * t * (1.0f + erff(t * 0.7071067811865475f));
        if (EPI == 2) { t = t * bnA + bnB; t = t > 0.f ? t : expm1f(t); }
        size_t o = (size_t)row * Nw + cw;
        if (OSPLIT) {
          u16 hh = f2b(t);
          Ch[o] = hh;
          Cl[o] = f2b(t - b2f(hh));
        } else {
          Cp[o] = t;
        }
      }
    }
  }
}

// ---------------- fused weight split/transpose (all weights, 1 dispatch) ---
// WATT layout per layer l: [qh kh vh oh][ql kl vl ol] (each 512x512) so the
// q,k,v high parts (and low parts) are contiguous for the fused QKV GEMM.
__global__ void k_splitall(const float* __restrict__ wq, const float* __restrict__ wk,
                           const float* __restrict__ wv, const float* __restrict__ wo,
                           const float* __restrict__ w1, const float* __restrict__ w2,
                           const float* __restrict__ cw,
                           u16* __restrict__ WATT, u16* __restrict__ W1T,
                           u16* __restrict__ W2T, u16* __restrict__ CWT) {
  int job = blockIdx.y;
  int g = blockIdx.x * 256 + threadIdx.x;
  float v;
  u16 *dh, *dl;
  if (job < 8) {
    if (g >= 262144) return;
    int l = job >> 2, mi = job & 3;
    const float* src = (mi == 0 ? wq : mi == 1 ? wk : mi == 2 ? wv : wo) + (size_t)l * 262144;
    int n = g >> 9, k = g & 511;
    v = src[(size_t)k * 512 + n];
    dh = WATT + (size_t)(l * 8 + mi) * 262144;
    dl = dh + 4 * 262144;
  } else if (job == 8 || job == 10) {           // w1: K=512, N=2048
    if (g >= 1048576) return;
    int l = (job == 10);
    int n = g >> 9, k = g & 511;
    v = w1[(size_t)l * 1048576 + (size_t)k * 2048 + n];
    dh = W1T + (size_t)(l * 2) * 1048576;
    dl = dh + 1048576;
  } else if (job == 9 || job == 11) {           // w2: K=2048, N=512
    if (g >= 1048576) return;
    int l = (job == 11);
    int n = g >> 11, k = g & 2047;
    v = w2[(size_t)l * 1048576 + (size_t)k * 512 + n];
    dh = W2T + (size_t)(l * 2) * 1048576;
    dl = dh + 1048576;
  } else {                                       // conv
    if (g >= 786432) return;
    int c = g / 1536, k = g - c * 1536;
    int kblk = k >> 9, ci = k & 511;
    v = cw[c * 1536 + ci * 3 + kblk];
    dh = CWT;
    dl = CWT + 786432;
  }
  u16 hh = f2b(v);
  dh[g] = hh;
  dl[g] = f2b(v - b2f(hh));
}

// ---------------- sampled qk -> sparsity measure M -------------------------
__global__ void k_qk_m(const float* __restrict__ Q, const float* __restrict__ Km,
                       const int* __restrict__ idx, float* __restrict__ Mout,
                       int Lc, int u) {
  int row = blockIdx.x;
  int b = row / Lc, l = row - b * Lc;
  int tid = threadIdx.x;
  int nt = blockDim.x;
  __shared__ __align__(16) float qlds[DMODEL];
  __shared__ int ilds[40];
  __shared__ float qk[320];
  for (int i = tid; i < DMODEL; i += nt) qlds[i] = Q[(size_t)row * DMODEL + i];
  for (int i = tid; i < u; i += nt) ilds[i] = idx[l * u + i];
  __syncthreads();
  int tot = NHEADS * u;
  if (tid < tot) {
    int j = tid >> 3, h = tid & 7;
    int key = ilds[j];
    const float4* kp = reinterpret_cast<const float4*>(&Km[((size_t)b * Lc + key) * DMODEL + h * DKH]);
    const float4* qp = reinterpret_cast<const float4*>(&qlds[h * DKH]);
    float s = 0.f;
#pragma unroll
    for (int d = 0; d < 16; d++) {
      float4 kv = kp[d], qv = qp[d];
      s += qv.x * kv.x + qv.y * kv.y + qv.z * kv.z + qv.w * kv.w;
    }
    qk[tid] = s;
  }
  __syncthreads();
  if (tid < NHEADS) {
    int h = tid;
    float mx = -INFINITY, sm = 0.f;
    for (int j = 0; j < u; j++) {
      float v = qk[(j << 3) + h];
      mx = fmaxf(mx, v);
      sm += v;
    }
    Mout[((size_t)b * NHEADS + h) * Lc + l] = mx - sm / (float)Lc;
  }
}

// ---------------- top-u: register-resident tournament ----------------------
// Keys live in 8 registers/thread (constant-indexed). Per iteration: wave
// shuffle reduce + 4-entry LDS combine; only the winner's owner rescans its
// 8 slots. Tie-break: key low word = ~index (lower index wins).
__global__ void k_topk(const float* __restrict__ Mv, int* __restrict__ mtop,
                       int Lc, int u) {
  int bh = blockIdx.x;
  int tid = threadIdx.x;
  int lane = tid & 63, wv = tid >> 6;
  __shared__ u64 wred[4];
  const int nk = Lc >> 8;           // 8 (Lc=2048) or 4 (Lc=1024)
  u64 kk[8];
#pragma unroll
  for (int e = 0; e < 8; e++) {
    u64 key = 0;
    if (e < nk) {
      int i = e * 256 + tid;
      u32 ub = __builtin_bit_cast(u32, Mv[(size_t)bh * Lc + i]);
      ub = (ub & 0x80000000u) ? ~ub : (ub | 0x80000000u);
      key = ((u64)ub << 32) | (u64)(0xFFFFFFFFu - (u32)i);
    }
    kk[e] = key;
  }
  u64 lm = kk[0];
#pragma unroll
  for (int e = 1; e < 8; e++) lm = lm > kk[e] ? lm : kk[e];
  for (int it = 0; it < u; it++) {
    u64 best = lm;
#pragma unroll
    for (int o = 32; o > 0; o >>= 1) {
      u64 other = __shfl_xor(best, o);
      best = best > other ? best : other;
    }
    if (lane == 0) wred[wv] = best;
    __syncthreads();
    u64 b01 = wred[0] > wred[1] ? wred[0] : wred[1];
    u64 b23 = wred[2] > wred[3] ? wred[2] : wred[3];
    u64 b0 = b01 > b23 ? b01 : b23;
    int bi = (int)(0xFFFFFFFFu - (u32)(b0 & 0xFFFFFFFFull));
    if (tid == 0) mtop[bh * u + it] = bi;
    int s = bi & 255, e = bi >> 8;
    if (tid == s) {
#pragma unroll
      for (int e2 = 0; e2 < 8; e2++)
        if (e2 == e) kk[e2] = 0;
      lm = kk[0];
#pragma unroll
      for (int e2 = 1; e2 < 8; e2++) lm = lm > kk[e2] ? lm : kk[e2];
    }
    __syncthreads();
  }
}

// ---------------- column-sum two-phase -------------------------------------
__global__ void k_colsum1(const float* __restrict__ src, float* __restrict__ part,
                          int Lc, int rp) {
  int b = blockIdx.x, ch = blockIdx.y, c = threadIdx.x;
  const float* p = src + ((size_t)b * Lc + (size_t)ch * rp) * 512 + c;
  float s = 0.f;
  for (int r = 0; r < rp; r++) s += p[(size_t)r * 512];
  part[((b << 5) + ch) * 512 + c] = s;
}
__global__ void k_colsum2(const float* __restrict__ part, float* __restrict__ of,
                          u16* __restrict__ oh, u16* __restrict__ ol,
                          int nch, float scale) {
  int b = blockIdx.x, c = threadIdx.x;
  float s = 0.f;
  for (int i = 0; i < nch; i++) s += part[(b * nch + i) * 512 + c];
  s *= scale;
  if (of) of[b * 512 + c] = s;
  if (oh) {
    u16 hh = f2b(s);
    oh[b * 512 + c] = hh;
    ol[b * 512 + c] = f2b(s - b2f(hh));
  }
}

// ---------------- fill context (bf16-split) with V-mean --------------------
__global__ void k_ctx_fillb(u16* __restrict__ ch, u16* __restrict__ cl,
                            const u16* __restrict__ vh, const u16* __restrict__ vl,
                            int Lc) {
  int g = blockIdx.x * 256 + threadIdx.x;
  int total = BATCH * Lc * 128;
  if (g >= total) return;
  int c4 = g & 127;
  int row = g >> 7;
  int b = row / Lc;
  ((ushort4*)ch)[g] = ((const ushort4*)vh)[b * 128 + c4];
  ((ushort4*)cl)[g] = ((const ushort4*)vl)[b * 128 + c4];
}

// ---------------- attention: 5 queries per block + scatter -----------------
__global__ __launch_bounds__(256) void k_attn_mq(
    const float* __restrict__ Q, const float* __restrict__ Km,
    const float* __restrict__ V, const int* __restrict__ mtop,
    u16* __restrict__ ctxh, u16* __restrict__ ctxl, int Lc, int u, int nqb) {
  int blk = blockIdx.x;
  int qb = blk % nqb;
  int bh = blk / nqb;
  int h = bh & 7, b = bh >> 3;
  int tid = threadIdx.x;
  int lane = tid & 63, wv = tid >> 6;
  __shared__ __align__(16) float qlds[5][64];
  __shared__ float s_lds[5][2048];
  __shared__ float wredA[4], wredB[4];
  __shared__ int rows_s[5];
  __shared__ float part[4][5][64];
  for (int qq = tid; qq < 320; qq += 256) {
    int q = qq >> 6, d = qq & 63;
    int row = mtop[(b * 8 + h) * u + qb * 5 + q];
    if (d == 0) rows_s[q] = row;
    qlds[q][d] = Q[((size_t)b * Lc + row) * DMODEL + h * DKH + d];
  }
  __syncthreads();
  for (int k = tid; k < Lc; k += 256) {
    const float4* kp = reinterpret_cast<const float4*>(&Km[((size_t)b * Lc + k) * DMODEL + h * DKH]);
    float s0 = 0, s1 = 0, s2 = 0, s3 = 0, s4 = 0;
#pragma unroll
    for (int d = 0; d < 16; d++) {
      float4 kv = kp[d];
      float4 q0 = ((const float4*)qlds[0])[d];
      float4 q1 = ((const float4*)qlds[1])[d];
      float4 q2 = ((const float4*)qlds[2])[d];
      float4 q3 = ((const float4*)qlds[3])[d];
      float4 q4 = ((const float4*)qlds[4])[d];
      s0 += q0.x * kv.x + q0.y * kv.y + q0.z * kv.z + q0.w * kv.w;
      s1 += q1.x * kv.x + q1.y * kv.y + q1.z * kv.z + q1.w * kv.w;
      s2 += q2.x * kv.x + q2.y * kv.y + q2.z * kv.z + q2.w * kv.w;
      s3 += q3.x * kv.x + q3.y * kv.y + q3.z * kv.z + q3.w * kv.w;
      s4 += q4.x * kv.x + q4.y * kv.y + q4.z * kv.z + q4.w * kv.w;
    }
    s_lds[0][k] = s0 * 0.125f;
    s_lds[1][k] = s1 * 0.125f;
    s_lds[2][k] = s2 * 0.125f;
    s_lds[3][k] = s3 * 0.125f;
    s_lds[4][k] = s4 * 0.125f;
  }
  __syncthreads();
  float denomv[5];
#pragma unroll
  for (int q = 0; q < 5; q++) {
    float mx = -INFINITY;
    for (int k = tid; k < Lc; k += 256) mx = fmaxf(mx, s_lds[q][k]);
#pragma unroll
    for (int o = 32; o > 0; o >>= 1) mx = fmaxf(mx, __shfl_xor(mx, o));
    if (lane == 0) wredA[wv] = mx;
    __syncthreads();
    mx = fmaxf(fmaxf(wredA[0], wredA[1]), fmaxf(wredA[2], wredA[3]));
    float ls = 0.f;
    for (int k = tid; k < Lc; k += 256) {
      float w = expf(s_lds[q][k] - mx);
      s_lds[q][k] = w;
      ls += w;
    }
#pragma unroll
    for (int o = 32; o > 0; o >>= 1) ls += __shfl_xor(ls, o);
    if (lane == 0) wredB[wv] = ls;
    __syncthreads();
    denomv[q] = (wredB[0] + wredB[1]) + (wredB[2] + wredB[3]);
  }
  float acc0 = 0, acc1 = 0, acc2 = 0, acc3 = 0, acc4 = 0;
  int chunk = Lc >> 2;
  for (int k = wv * chunk; k < (wv + 1) * chunk; k++) {
    float vvv = V[((size_t)b * Lc + k) * DMODEL + h * DKH + lane];
    acc0 = fmaf(s_lds[0][k], vvv, acc0);
    acc1 = fmaf(s_lds[1][k], vvv, acc1);
    acc2 = fmaf(s_lds[2][k], vvv, acc2);
    acc3 = fmaf(s_lds[3][k], vvv, acc3);
    acc4 = fmaf(s_lds[4][k], vvv, acc4);
  }
  part[wv][0][lane] = acc0;
  part[wv][1][lane] = acc1;
  part[wv][2][lane] = acc2;
  part[wv][3][lane] = acc3;
  part[wv][4][lane] = acc4;
  __syncthreads();
  for (int q = wv; q < 5; q += 4) {
    float tot = ((part[0][q][lane] + part[1][q][lane]) +
                 (part[2][q][lane] + part[3][q][lane])) / denomv[q];
    size_t o = ((size_t)b * Lc + rows_s[q]) * DMODEL + h * DKH + lane;
    u16 hh = f2b(tot);
    ctxh[o] = hh;
    ctxl[o] = f2b(tot - b2f(hh));
  }
}

// ---------------- y = LayerNorm(x+a)*g+b ; optional fp32 / split out -------
__global__ void k_add_ln(const float* __restrict__ x, const float* __restrict__ a,
                         const float* __restrict__ g, const float* __restrict__ be,
                         float* __restrict__ y, u16* __restrict__ yh,
                         u16* __restrict__ yl) {
  int row = blockIdx.x;
  int tid = threadIdx.x;
  __shared__ float red[256];
  float2 xv = reinterpret_cast<const float2*>(x)[(size_t)row * 256 + tid];
  float2 av = reinterpret_cast<const float2*>(a)[(size_t)row * 256 + tid];
  float vx = xv.x + av.x, vy = xv.y + av.y;
  red[tid] = vx + vy;
  __syncthreads();
  for (int s = 128; s > 0; s >>= 1) {
    if (tid < s) red[tid] += red[tid + s];
    __syncthreads();
  }
  float mean = red[0] * (1.0f / 512.0f);
  __syncthreads();
  float dx = vx - mean, dy = vy - mean;
  red[tid] = dx * dx + dy * dy;
  __syncthreads();
  for (int s = 128; s > 0; s >>= 1) {
    if (tid < s) red[tid] += red[tid + s];
    __syncthreads();
  }
  float rstd = rsqrtf(red[0] * (1.0f / 512.0f) + 1e-5f);
  int c = tid * 2;
  float ox = dx * rstd * g[c] + be[c];
  float oy = dy * rstd * g[c + 1] + be[c + 1];
  if (y) {
    float2 o = {ox, oy};
    reinterpret_cast<float2*>(y)[(size_t)row * 256 + tid] = o;
  }
  if (yh) {
    size_t base = (size_t)row * 512 + c;
    u16 h0 = f2b(ox), h1 = f2b(oy);
    yh[base] = h0; yh[base + 1] = h1;
    yl[base] = f2b(ox - b2f(h0));
    yl[base + 1] = f2b(oy - b2f(h1));
  }
}

// ---------------- maxpool k=3 s=2, fp32 + split out ------------------------
__global__ void k_pool(const float* __restrict__ cv, float* __restrict__ out,
                       u16* __restrict__ oh, u16* __restrict__ ol) {
  int g = blockIdx.x * 256 + threadIdx.x;
  int total = BATCH * LL2 * DMODEL;
  if (g >= total) return;
  int c = g & 511;
  int rest = g >> 9;
  int i = rest & (LL2 - 1);
  int b = rest >> 10;
  int t0 = 2 * i - 1;
  float m = -INFINITY;
#pragma unroll
  for (int k = 0; k < 3; k++) {
    int t = t0 + k;
    if (t >= 0 && t < LL1) m = fmaxf(m, cv[((size_t)b * LL1 + t) * DMODEL + c]);
  }
  out[g] = m;
  u16 hh = f2b(m);
  oh[g] = hh;
  ol[g] = f2b(m - b2f(hh));
}

// ---------------- gx = enc @ wih^T + bih (+ zero lstm tag buffer) ----------
__global__ void k_gx(const float* __restrict__ enc, const float* __restrict__ wih,
                     const float* __restrict__ bih, float* __restrict__ gx,
                     u64* __restrict__ hgl) {
  int g = blockIdx.x * 256 + threadIdx.x;
  if (g < 8192) hgl[g] = 0ull;                      // zero tags (both parities)
  if (g >= BATCH * 2048) return;
  int b = g >> 11, j = g & 2047;
  const float4* wp = reinterpret_cast<const float4*>(&wih[(size_t)j * 512]);
  const float4* ep = reinterpret_cast<const float4*>(&enc[b * 512]);
  float s = bih[j];
  for (int d = 0; d < 128; d++) {
    float4 w = wp[d], e = ep[d];
    s += w.x * e.x + w.y * e.y + w.z * e.z + w.w * e.w;
  }
  gx[g] = s;
}

// ---------------- persistent LSTM v5: tagged-u64 single-RT exchange --------
__global__ __launch_bounds__(256, 1) void k_lstm5(
    const float* __restrict__ gx, const float* __restrict__ whh,
    const float* __restrict__ bhh, const float* __restrict__ ow,
    const float* __restrict__ ob, float* __restrict__ out,
    u64* __restrict__ hglob) {
  const int bl = blockIdx.x, tid = threadIdx.x;
  const int part = tid >> 5, idx = tid & 31;       // part: 64-chunk of k
  const int gtype = idx >> 3, ml = idx & 7;
  const int j = gtype * 512 + bl * 8 + ml;          // owned gate row
  __shared__ float h_s[4096];                       // [b][512]
  __shared__ float red[8][8][32];                   // [b][part][idx]
  __shared__ float gvs[8][32];                      // [b][idx]
  __shared__ float ow_s[512];
  __shared__ float ored[4];
  float w[64];
  {
    const float* wr = &whh[(size_t)j * 512 + part * 64];
#pragma unroll
    for (int r = 0; r < 64; r += 4) {
      float4 v = *(const float4*)&wr[r];
      w[r] = v.x; w[r + 1] = v.y; w[r + 2] = v.z; w[r + 3] = v.w;
    }
  }
  const float gxrow = gx[part * 2048 + j] + bhh[j];  // (b=part, row j)
  float cst = 0.f;                                    // live on tid<64
  for (int i = tid; i < 4096; i += 256) h_s[i] = 0.f;
  for (int i = tid; i < 512; i += 256) ow_s[i] = ow[i];
  const float obv = ob[0];
  __syncthreads();
  for (int t = 0; t < TPRED; t++) {
    float p[8];
#pragma unroll
    for (int b = 0; b < 8; b++) p[b] = 0.f;
#pragma unroll
    for (int r = 0; r < 64; r += 4) {
      float w0 = w[r], w1 = w[r + 1], w2 = w[r + 2], w3 = w[r + 3];
#pragma unroll
      for (int b = 0; b < 8; b++) {
        float4 hv = *(const float4*)&h_s[b * 512 + part * 64 + r];
        p[b] = fmaf(w3, hv.w, fmaf(w2, hv.z, fmaf(w1, hv.y, fmaf(w0, hv.x, p[b]))));
      }
    }
#pragma unroll
    for (int b = 0; b < 8; b++) red[b][part][idx] = p[b];
    __syncthreads();
    float gv = gxrow;                                 // (b=part, row idx)
#pragma unroll
    for (int pp = 0; pp < 8; pp++) gv += red[part][pp][idx];
    gvs[part][idx] = gv;                              // [b][idx]
    __syncthreads();
    u64* hgb = hglob + ((t + 1) & 1) * 4096;          // parity buffer
    const u32 want = (u32)(t + 1);
    if (tid < 64) {                                   // (b, ml) owners
      int b = tid >> 3, m = tid & 7;
      float gi = gvs[b][m], gf = gvs[b][8 + m];
      float gg = gvs[b][16 + m], go = gvs[b][24 + m];
      float c = sigm(gf) * cst + sigm(gi) * tanhf(gg);
      cst = c;
      float hn = sigm(go) * tanhf(c);
      u64 word = ((u64)want << 32) | (u64)__builtin_bit_cast(u32, hn);
      __hip_atomic_store(&hgb[b * 512 + bl * 8 + m], word, __ATOMIC_RELAXED,
                         __HIP_MEMORY_SCOPE_AGENT);
    }
    {
      u64 v[16];
#pragma unroll
      for (int q = 0; q < 16; q++)
        v[q] = __hip_atomic_load(&hgb[q * 256 + tid], __ATOMIC_RELAXED,
                                 __HIP_MEMORY_SCOPE_AGENT);
      bool ok;
      do {
        ok = true;
#pragma unroll
        for (int q = 0; q < 16; q++) {
          if ((u32)(v[q] >> 32) != want) {
            ok = false;
            v[q] = __hip_atomic_load(&hgb[q * 256 + tid], __ATOMIC_RELAXED,
                                     __HIP_MEMORY_SCOPE_AGENT);
          }
        }
      } while (!ok);
#pragma unroll
      for (int q = 0; q < 16; q++)
        h_s[q * 256 + tid] = __builtin_bit_cast(float, (u32)(v[q] & 0xFFFFFFFFull));
    }
    __syncthreads();
    if (bl < 8) {                                     // output dot for batch bl
      float s = h_s[bl * 512 + tid] * ow_s[tid] +
                h_s[bl * 512 + 256 + tid] * ow_s[256 + tid];
#pragma unroll
      for (int o = 32; o > 0; o >>= 1) s += __shfl_xor(s, o);
      if ((tid & 63) == 0) ored[tid >> 6] = s;
      __syncthreads();
      if (tid == 0)
        out[bl * TPRED + t] = (ored[0] + ored[1]) + (ored[2] + ored[3]) + obv;
    }
  }
}

// ---------------------------------------------------------------------------
extern "C" void kernel_launch(void* const* d_in, const int* in_sizes, int n_in,
                              void* d_out, int out_size, void* d_ws, size_t ws_size,
                              hipStream_t stream) {
  const float* x = (const float*)d_in[0];
  const int* idx1 = (const int*)d_in[1];
  const int* idx2 = (const int*)d_in[2];
  const float* emb_w = (const float*)d_in[3];
  const float* emb_b = (const float*)d_in[4];
  const float* wq = (const float*)d_in[5];
  const float* bq = (const float*)d_in[6];
  const float* wk = (const float*)d_in[7];
  const float* bk = (const float*)d_in[8];
  const float* wv = (const float*)d_in[9];
  const float* bv = (const float*)d_in[10];
  const float* wo = (const float*)d_in[11];
  const float* bo = (const float*)d_in[12];
  const float* w1 = (const float*)d_in[13];
  const float* b1 = (const float*)d_in[14];
  const float* w2 = (const float*)d_in[15];
  const float* b2 = (const float*)d_in[16];
  const float* ln1g = (const float*)d_in[17];
  const float* ln1b = (const float*)d_in[18];
  const float* ln2g = (const float*)d_in[19];
  const float* ln2b = (const float*)d_in[20];
  const float* conv_w = (const float*)d_in[21];
  const float* conv_b = (const float*)d_in[22];
  const float* bn_g = (const float*)d_in[23];
  const float* bn_b = (const float*)d_in[24];
  const float* bn_m = (const float*)d_in[25];
  const float* bn_v = (const float*)d_in[26];
  const float* lstm_wih = (const float*)d_in[27];
  const float* lstm_whh = (const float*)d_in[28];
  const float* lstm_bih = (const float*)d_in[29];
  const float* lstm_bhh = (const float*)d_in[30];
  const float* out_w = (const float*)d_in[31];
  const float* out_b = (const float*)d_in[32];
  float* outp = (float*)d_out;

  char* ws = (char*)d_ws;
  const size_t MB = 1 << 20;
  float* S0 = (float*)(ws);
  float* S1 = (float*)(ws + 32 * MB);
  float* S2 = (float*)(ws + 64 * MB);
  float* S3 = (float*)(ws + 96 * MB);
  u16* P0 = (u16*)(ws + 128 * MB);
  u16* P1 = (u16*)(ws + 144 * MB);
  u16* P2 = (u16*)(ws + 160 * MB);
  u16* P3 = (u16*)(ws + 176 * MB);
  u16* WATT = (u16*)(ws + 192 * MB);
  u16* W1T = (u16*)(ws + 200 * MB);
  u16* W2T = (u16*)(ws + 208 * MB);
  u16* CWT = (u16*)(ws + 216 * MB);
  char* SMB = ws + 220 * MB;
  float* Mbuf = (float*)(SMB);                       // 512 KB
  float* csp = (float*)(SMB + 512 * 1024);           // 512 KB
  u16* vmh = (u16*)(SMB + 1040 * 1024);
  u16* vml = (u16*)(SMB + 1048 * 1024);
  int* mtop = (int*)(SMB + 1056 * 1024);
  float* gxb = (float*)(SMB + 1088 * 1024);          // 64 KB
  float* encb = (float*)(SMB + 1152 * 1024);
  u64* hglob = (u64*)(SMB + 1168 * 1024);            // 64 KB (2x4096 u64)

  auto wat = [&](int l, int m, int hl) {
    return WATT + ((size_t)(l * 8 + hl * 4 + m)) * 262144;
  };

  // fused weight split (single dispatch)
  {
    dim3 g(4096, 13);
    k_splitall<<<g, 256, 0, stream>>>(wq, wk, wv, wo, w1, w2, conv_w,
                                      WATT, W1T, W2T, CWT);
  }

  auto mg = [&](const u16* Ah, const u16* Al, const u16* Bh, const u16* Bl,
                const float* bias, float* C, int M, int N, int K) {
    dim3 g(N / 128, M / 128);
    k_mgemm<0, 0, 0, 0><<<g, 256, 0, stream>>>(
        Ah, Al, Bh, Bl, bias, nullptr, nullptr, C, nullptr, nullptr,
        nullptr, nullptr, M, N, K, 0, nullptr, nullptr, nullptr, nullptr);
  };
  auto mg3 = [&](const u16* Ah, const u16* Al, const u16* Bh, const u16* Bl,
                 const float* b0_, const float* b1_, const float* b2_,
                 float* C0_, float* C1_, float* C2_, int M) {
    dim3 g(12, M / 128);
    k_mgemm<0, 0, 0, 1><<<g, 256, 0, stream>>>(
        Ah, Al, Bh, Bl, b0_, b1_, b2_, C0_, C1_, C2_,
        nullptr, nullptr, M, 1536, 512, 0, nullptr, nullptr, nullptr, nullptr);
  };

  // ---------------- embed ----------------
  k_embed<<<(BATCH * LL1) / 8, 256, 0, stream>>>(x, emb_w, emb_b, S0, P0, P1);

  // ---------------- encoder layer 1 (L=2048, u=40) ----------------
  {
    const int Lc = LL1, u = 40, M = BATCH * LL1;
    mg3(P0, P1, wat(0, 0, 0), wat(0, 0, 1), bq, bk, bv, S1, S2, S3, M);
    k_qk_m<<<M, 320, 0, stream>>>(S1, S2, idx1, Mbuf, Lc, u);
    k_topk<<<64, 256, 0, stream>>>(Mbuf, mtop, Lc, u);
    k_colsum1<<<dim3(BATCH, 32), 512, 0, stream>>>(S3, csp, Lc, Lc / 32);
    k_colsum2<<<BATCH, 512, 0, stream>>>(csp, nullptr, vmh, vml, 32, 1.f / Lc);
    k_ctx_fillb<<<(BATCH * Lc * 128) / 256, 256, 0, stream>>>(P2, P3, vmh, vml, Lc);
    k_attn_mq<<<64 * 8, 256, 0, stream>>>(S1, S2, S3, mtop, P2, P3, Lc, u, 8);
    mg(P2, P3, wat(0, 3, 0), wat(0, 3, 1), bo, S1, M, 512, 512);
    k_add_ln<<<M, 256, 0, stream>>>(S0, S1, ln1g, ln1b, S2, P0, P1);
    u16* hidh = (u16*)S0;
    u16* hidl = (u16*)S1;
    for (int c = 0; c < 2; c++) {
      dim3 g1(16, 64);
      k_mgemm<1, 0, 1, 0><<<g1, 256, 0, stream>>>(
          P0 + (size_t)c * 8192 * 512, P1 + (size_t)c * 8192 * 512,
          W1T, W1T + 1048576, b1, nullptr, nullptr, nullptr, nullptr, nullptr,
          hidh, hidl, 8192, 2048, 512, 0, nullptr, nullptr, nullptr, nullptr);
      dim3 g2(4, 64);
      k_mgemm<0, 0, 0, 0><<<g2, 256, 0, stream>>>(
          hidh, hidl, W2T, W2T + 1048576, b2, nullptr, nullptr,
          S3 + (size_t)c * 8192 * 512, nullptr, nullptr, nullptr, nullptr,
          8192, 512, 2048, 0, nullptr, nullptr, nullptr, nullptr);
    }
    k_add_ln<<<M, 256, 0, stream>>>(S2, S3, ln2g, ln2b, nullptr, P0, P1);
  }

  // ---------------- conv distill ----------------
  {
    dim3 g(4, 128);
    k_mgemm<2, 1, 0, 0><<<g, 256, 0, stream>>>(
        P0, P1, CWT, CWT + 786432, conv_b, nullptr, nullptr,
        S1, nullptr, nullptr, nullptr, nullptr, 16384, 512, 1536,
        LL1, bn_m, bn_v, bn_g, bn_b);
    k_pool<<<(BATCH * LL2 * 512) / 256, 256, 0, stream>>>(S1, S2, P0, P1);
  }

  // ---------------- encoder layer 2 (L=1024, u=35) ----------------
  {
    const int Lc = LL2, u = 35, M = BATCH * LL2;
    float* Qb = S1;
    float* Kb = S1 + 4194304;
    float* Vb = S3;
    float* AOb = S3 + 4194304;
    mg3(P0, P1, wat(1, 0, 0), wat(1, 0, 1), bq + 512, bk + 512, bv + 512,
        Qb, Kb, Vb, M);
    k_qk_m<<<M, 320, 0, stream>>>(Qb, Kb, idx2, Mbuf, Lc, u);
    k_topk<<<64, 256, 0, stream>>>(Mbuf, mtop, Lc, u);
    k_colsum1<<<dim3(BATCH, 32), 512, 0, stream>>>(Vb, csp, Lc, Lc / 32);
    k_colsum2<<<BATCH, 512, 0, stream>>>(csp, nullptr, vmh, vml, 32, 1.f / Lc);
    k_ctx_fillb<<<(BATCH * Lc * 128) / 256, 256, 0, stream>>>(P2, P3, vmh, vml, Lc);
    k_attn_mq<<<64 * 7, 256, 0, stream>>>(Qb, Kb, Vb, mtop, P2, P3, Lc, u, 7);
    mg(P2, P3, wat(1, 3, 0), wat(1, 3, 1), bo + 512, AOb, M, 512, 512);
    k_add_ln<<<M, 256, 0, stream>>>(S2, AOb, ln1g + 512, ln1b + 512, S0, P0, P1);
    u16* hidh = (u16*)S1;
    u16* hidl = (u16*)S3;
    {
      dim3 g1(16, 64);
      k_mgemm<1, 0, 1, 0><<<g1, 256, 0, stream>>>(
          P0, P1, W1T + (size_t)2 * 1048576, W1T + (size_t)3 * 1048576,
          b1 + 2048, nullptr, nullptr, nullptr, nullptr, nullptr,
          hidh, hidl, 8192, 2048, 512, 0, nullptr, nullptr, nullptr, nullptr);
      dim3 g2(4, 64);
      k_mgemm<0, 0, 0, 0><<<g2, 256, 0, stream>>>(
          hidh, hidl, W2T + (size_t)2 * 1048576, W2T + (size_t)3 * 1048576,
          b2 + 512, nullptr, nullptr, S2, nullptr, nullptr, nullptr, nullptr,
          8192, 512, 2048, 0, nullptr, nullptr, nullptr, nullptr);
    }
    k_add_ln<<<M, 256, 0, stream>>>(S0, S2, ln2g + 512, ln2b + 512, S3, nullptr, nullptr);
  }

  // ---------------- mean -> LSTM -> output ----------------
  k_colsum1<<<dim3(BATCH, 32), 512, 0, stream>>>(S3, csp, LL2, LL2 / 32);
  k_colsum2<<<BATCH, 512, 0, stream>>>(csp, encb, nullptr, nullptr, 32, 1.f / LL2);
  k_gx<<<(BATCH * 2048) / 256, 256, 0, stream>>>(encb, lstm_wih, lstm_bih, gxb, hglob);
  k_lstm5<<<64, 256, 0, stream>>>(gxb, lstm_whh, lstm_bhh, out_w, out_b, outp, hglob);
}